// Round 9
// baseline (117.135 us; speedup 1.0000x reference)
//
#include <hip/hip_runtime.h>

#define B_ 2
#define T_ 2048
#define C_ 1024
#define H_ 16
#define HD_ 64

typedef unsigned short u16;
typedef unsigned int u32;
typedef __attribute__((ext_vector_type(8))) short short8;
typedef __attribute__((ext_vector_type(4))) float f32x4;
typedef __attribute__((ext_vector_type(2))) u32 uint2v;
typedef __attribute__((ext_vector_type(4))) u32 uint4v;

typedef __attribute__((address_space(1))) const void* as1cv;
typedef __attribute__((address_space(3))) void* as3v;

__device__ __forceinline__ u16 f2bf(float x){
  union { float f; u32 u; } v; v.f = x;
  u32 r = v.u + 0x7fffu + ((v.u >> 16) & 1u);
  return (u16)(r >> 16);
}
__device__ __forceinline__ float bf2f(u16 h){
  union { u32 u; float f; } v; v.u = ((u32)h) << 16;
  return v.f;
}
// packed f32x2 -> bf16x2 (RTNE), single VALU inst
__device__ __forceinline__ u32 cvt_pk_bf16(float lo, float hi){
  u32 r;
  asm("v_cvt_pk_bf16_f32 %0, %1, %2" : "=v"(r) : "v"(lo), "v"(hi));
  return r;
}
__device__ __forceinline__ void gl_lds16(const u16* src, u16* dst){
  __builtin_amdgcn_global_load_lds((as1cv)src, (as3v)dst, 16, 0, 0);
}

// ---------------- f32 -> bf16 convert (x4 vectorized) ----------------
__global__ void k_conv(const float* __restrict__ in, u16* __restrict__ out){
  int i = blockIdx.x * 256 + threadIdx.x;
  f32x4 v = ((const f32x4*)in)[i];
  uint2v o;
  o.x = (u32)f2bf(v.x) | ((u32)f2bf(v.y) << 16);
  o.y = (u32)f2bf(v.z) | ((u32)f2bf(v.w) << 16);
  ((uint2v*)out)[i] = o;
}

// ------------- transpose + convert: out[c][r] = bf16(in[r][c]) -------------
__global__ void k_transpose(const float* __restrict__ in, u16* __restrict__ out,
                            int R, int Cc){
  __shared__ float tile[32][33];
  int c0 = blockIdx.x * 32, r0 = blockIdx.y * 32;
  int tx = threadIdx.x, ty = threadIdx.y;
#pragma unroll
  for (int ii = 0; ii < 4; ++ii)
    tile[ty + ii*8][tx] = in[(size_t)(r0 + ty + ii*8) * Cc + c0 + tx];
  __syncthreads();
#pragma unroll
  for (int ii = 0; ii < 4; ++ii)
    out[(size_t)(c0 + ty + ii*8) * R + r0 + tx] = f2bf(tile[tx][ty + ii*8]);
}

// ---------------- QKV GEMM + fused RoPE epilogue ----------------
// C[M=4096][N=3072] = A * Bt^T + bias.  BM=BN=128, BK=64, 4 waves.
// T3 minimum-2-phase counted loop: stage NEXT K-tile first (into other buffer),
// compute CURRENT tile, then ONE __syncthreads per K-tile — its implicit
// vmcnt(0) drain has a full compute phase of slack (vs R8's drain-at-issue).
// One fused LDS array [A0|A1|B0|B1] so all staged offsets derive from one symbol.
// Q cols (<1024):   RoPE + scale(0.125*log2e) -> Qh[bh][t][64] bf16
// K cols (1024..2048): RoPE -> Kh[bh][t][64] bf16
// V cols (>=2048):  transposed -> Vt[bh][d][t] bf16
__global__ __launch_bounds__(256, 2)
void k_gemm0(const u16* __restrict__ A, const u16* __restrict__ Bt,
             const float* __restrict__ bias, u16* __restrict__ Qh,
             u16* __restrict__ Kh, u16* __restrict__ vt,
             int M, int N, int K)
{
  __shared__ u16 LDSG[32768];              // [A0|A1|B0|B1], 16KB each
  int nwg = gridDim.x;
  int cpx = nwg >> 3;
  int bid = blockIdx.x;
  int wg = (bid & 7) * cpx + (bid >> 3);   // bijective XCD swizzle (nwg%8==0)
  int ntn = N >> 7;
  int m0 = (wg / ntn) << 7, n0 = (wg % ntn) << 7;
  int tid = threadIdx.x;
  int lane = tid & 63, w = tid >> 6;
  int c = lane & 15, g = lane >> 4;
  int wr = w >> 1, wc = w & 1;

  f32x4 z4 = {0.f,0.f,0.f,0.f};
  f32x4 acc[4][4];
#pragma unroll
  for (int i=0;i<4;++i)
#pragma unroll
    for (int j=0;j<4;++j) acc[i][j] = z4;

  // staging maps (fixed across K-tiles)
  int rowS[4], slotS[4], dstS[4];
#pragma unroll
  for (int it=0; it<4; ++it){
    int ch = it*256 + tid;
    rowS[it] = ch >> 3;
    slotS[it] = (ch & 7) * 8;
    dstS[it] = it*2048 + ((tid & 0xC0) << 3);   // wave-uniform linear dest
  }
  const u16* Abase = A + (size_t)m0*K;
  const u16* Bbase = Bt + (size_t)n0*K;

  // prologue: stage K-tile 0 into buf 0
#pragma unroll
  for (int it=0; it<4; ++it){
    gl_lds16(Abase + (size_t)rowS[it]*K + slotS[it], LDSG + dstS[it]);
    gl_lds16(Bbase + (size_t)rowS[it]*K + slotS[it], LDSG + 16384 + dstS[it]);
  }
  __syncthreads();

  int nk = K >> 6;
  for (int kt = 0; kt < nk; ++kt){
    int cur = kt & 1;
    if (kt + 1 < nk){
      int k1 = (kt + 1) << 6;
      int nb = cur ^ 1;
#pragma unroll
      for (int it=0; it<4; ++it){
        gl_lds16(Abase + (size_t)rowS[it]*K + k1 + slotS[it], LDSG + nb*8192 + dstS[it]);
        gl_lds16(Bbase + (size_t)rowS[it]*K + k1 + slotS[it], LDSG + 16384 + nb*8192 + dstS[it]);
      }
    }
    const u16* As = LDSG + cur*8192;
    const u16* Bs = LDSG + 16384 + cur*8192;
#pragma unroll
    for (int ks = 0; ks < 2; ++ks){
      short8 af[4], bf[4];
#pragma unroll
      for (int i=0;i<4;++i)
        af[i] = *(const short8*)(As + (wr*64 + i*16 + c)*64 + ks*32 + g*8);
#pragma unroll
      for (int j=0;j<4;++j)
        bf[j] = *(const short8*)(Bs + (wc*64 + j*16 + c)*64 + ks*32 + g*8);
#pragma unroll
      for (int i=0;i<4;++i)
#pragma unroll
        for (int j=0;j<4;++j)
          acc[i][j] = __builtin_amdgcn_mfma_f32_16x16x32_bf16(af[i], bf[j], acc[i][j], 0, 0, 0);
    }
    __syncthreads();   // single barrier/K-tile; vmcnt(0) drain has full-phase slack
  }

  if (n0 >= 2048){
    // V section -> vt[bh][d][t], 4 consecutive t packed per 8B store
#pragma unroll
    for (int i=0;i<4;++i){
      int rowb = m0 + wr*64 + i*16 + g*4;
      int bb = rowb >> 11, t0 = rowb & 2047;
#pragma unroll
      for (int j=0;j<4;++j){
        int col = n0 + wc*64 + j*16 + c;
        float bv = bias[col];
        int vc = col - 2048;
        int hh = vc >> 6, d = vc & 63;
        uint2v o;
        o.x = (u32)f2bf(acc[i][j].x + bv) | ((u32)f2bf(acc[i][j].y + bv) << 16);
        o.y = (u32)f2bf(acc[i][j].z + bv) | ((u32)f2bf(acc[i][j].w + bv) << 16);
        *(uint2v*)(vt + ((size_t)((bb*16 + hh)*64 + d))*2048 + t0) = o;
      }
    }
  } else {
    // Q/K section: fused RoPE + head-split write
    bool isQ = (n0 < 1024);
    u16* dsth = isQ ? Qh : Kh;
    int colb = isQ ? n0 : (n0 - 1024);
    float qsc = isQ ? 0.180336880f : 1.0f;  // 0.125 * log2(e) on Q only
    float sgn = (c & 1) ? 1.f : -1.f;
#pragma unroll
    for (int nf=0; nf<4; ++nf){
      int scol = colb + wc*64 + nf*16 + c;
      int hh = scol >> 6, d = scol & 63;
      int ip = (d >> 1);
      float invr = exp2f((float)(-ip) * 0.4152410118609203f) * 0.15915494309f;
      float bv = bias[n0 + wc*64 + nf*16 + c];
      u16* base = dsth + (size_t)hh*2048*64 + d;
#pragma unroll
      for (int mf=0; mf<4; ++mf){
#pragma unroll
        for (int r=0; r<4; ++r){
          int row = m0 + wr*64 + mf*16 + g*4 + r;
          int t = row & 2047, b = row >> 11;
          float v = acc[mf][nf][r] + bv;
          float p = __shfl_xor(v, 1);
          float th = (float)t * invr;
          float fr = th - floorf(th);
          float sn = __builtin_amdgcn_sinf(fr);
          float cs = __builtin_amdgcn_cosf(fr);
          float y = (v*cs + p*sn*sgn) * qsc;
          base[((size_t)b*16*2048 + t)*64] = f2bf(y);
        }
      }
    }
  }
}

// ---------------- proj GEMM: out = Y * Wp^T + bias ----------------
// 128x128 tile, grid 256 (exactly 1 round), same counted-loop structure.
__global__ __launch_bounds__(256, 2)
void k_gemmp(const u16* __restrict__ A, const u16* __restrict__ Bt,
             const float* __restrict__ bias, float* __restrict__ outf)
{
  __shared__ u16 LDSG[32768];              // [A0|A1|B0|B1]
  const int K = 1024, N = 1024;
  int nwg = gridDim.x;                     // 256
  int cpx = nwg >> 3;
  int bid = blockIdx.x;
  int wg = (bid & 7) * cpx + (bid >> 3);
  int m0 = (wg >> 3) << 7, n0 = (wg & 7) << 7;
  int tid = threadIdx.x;
  int lane = tid & 63, w = tid >> 6;
  int c = lane & 15, g = lane >> 4;
  int wr = w >> 1, wc = w & 1;

  f32x4 z4 = {0.f,0.f,0.f,0.f};
  f32x4 acc[4][4];
#pragma unroll
  for (int i=0;i<4;++i)
#pragma unroll
    for (int j=0;j<4;++j) acc[i][j] = z4;

  int rowS[4], slotS[4], dstS[4];
#pragma unroll
  for (int it=0; it<4; ++it){
    int ch = it*256 + tid;
    rowS[it] = ch >> 3;
    slotS[it] = (ch & 7) * 8;
    dstS[it] = it*2048 + ((tid & 0xC0) << 3);
  }
  const u16* Abase = A + (size_t)m0*K;
  const u16* Bbase = Bt + (size_t)n0*K;

#pragma unroll
  for (int it=0; it<4; ++it){
    gl_lds16(Abase + (size_t)rowS[it]*K + slotS[it], LDSG + dstS[it]);
    gl_lds16(Bbase + (size_t)rowS[it]*K + slotS[it], LDSG + 16384 + dstS[it]);
  }
  __syncthreads();

  const int nk = K >> 6;
  for (int kt = 0; kt < nk; ++kt){
    int cur = kt & 1;
    if (kt + 1 < nk){
      int k1 = (kt + 1) << 6;
      int nb = cur ^ 1;
#pragma unroll
      for (int it=0; it<4; ++it){
        gl_lds16(Abase + (size_t)rowS[it]*K + k1 + slotS[it], LDSG + nb*8192 + dstS[it]);
        gl_lds16(Bbase + (size_t)rowS[it]*K + k1 + slotS[it], LDSG + 16384 + nb*8192 + dstS[it]);
      }
    }
    const u16* As = LDSG + cur*8192;
    const u16* Bs = LDSG + 16384 + cur*8192;
#pragma unroll
    for (int ks = 0; ks < 2; ++ks){
      short8 af[4], bf[4];
#pragma unroll
      for (int i=0;i<4;++i)
        af[i] = *(const short8*)(As + (wr*64 + i*16 + c)*64 + ks*32 + g*8);
#pragma unroll
      for (int j=0;j<4;++j)
        bf[j] = *(const short8*)(Bs + (wc*64 + j*16 + c)*64 + ks*32 + g*8);
#pragma unroll
      for (int i=0;i<4;++i)
#pragma unroll
        for (int j=0;j<4;++j)
          acc[i][j] = __builtin_amdgcn_mfma_f32_16x16x32_bf16(af[i], bf[j], acc[i][j], 0, 0, 0);
    }
    __syncthreads();
  }

#pragma unroll
  for (int i=0;i<4;++i){
#pragma unroll
    for (int j=0;j<4;++j){
      int col = n0 + wc*64 + j*16 + c;
      float bv = bias[col];
#pragma unroll
      for (int r=0;r<4;++r){
        int row = m0 + wr*64 + i*16 + g*4 + r;
        outf[(size_t)row*N + col] = acc[i][j][r] + bv;
      }
    }
  }
}

// ---------------- causal flash attention, KV-split x4, 4-wave blocks ----------------
// Qh,Kh: [bh][t][64] bf16 (Q pre-scaled, log2 domain).  Vt: [bh][64][t] bf16.
// Grid: 2048 blocks of 256 threads (4 waves x 32 q-rows = 128 q-rows/block).
// FIXED-MAX softmax (m=0). Partials: bf16 O + f32 row sums; k_merge sums 4 chunks.
__global__ __launch_bounds__(256, 3)
void k_attn(const u16* __restrict__ Qh, const u16* __restrict__ Kh,
            const u16* __restrict__ Vt, u16* __restrict__ Pb,
            float* __restrict__ lp)
{
  __shared__ u16 KV[4*4096];     // [K0 | K1 | V0 | V1], XOR-swizzled 16B chunks
  __shared__ u16 Ps[4*32*64];    // per-wave P[q][kv], XOR-swizzled

  int bid = blockIdx.x;
  int qt = 15 - (bid >> 7);
  int r7 = bid & 127;
  int ck = r7 >> 5, bh = r7 & 31;
  int q0 = qt << 7;
  int tid = threadIdx.x, lane = tid & 63, w = tid >> 6;
  int c = lane & 15, g = lane >> 4;
  int q0w = q0 + w*32;
  int nt = (qt + 1) << 1;
  int t0 = (nt * ck) >> 2;
  int t1 = (nt * (ck + 1)) >> 2;

  const u16* Kbase = Kh + (size_t)bh * T_ * 64;
  const u16* Vbase = Vt + (size_t)bh * 64 * T_;
  const u16* Qbase = Qh + (size_t)bh * T_ * 64;

  short8 qf[2][2];
#pragma unroll
  for (int qs=0;qs<2;++qs)
#pragma unroll
    for (int ks=0;ks<2;++ks)
      qf[qs][ks] = *(const short8*)(Qbase + (size_t)(q0w + qs*16 + c)*64 + ks*32 + g*8);

  f32x4 z4 = {0.f,0.f,0.f,0.f};
  f32x4 acc[2][4];
#pragma unroll
  for (int qs=0;qs<2;++qs)
#pragma unroll
    for (int ds=0;ds<4;++ds) acc[qs][ds] = z4;
  float psum[2] = {0.f, 0.f};

  char* PsB = (char*)Ps + w*4096;

  int row2[2], soff2[2];
  u16* dst0[2];
#pragma unroll
  for (int it=0; it<2; ++it){
    int ch = it*256 + tid;
    row2[it] = ch >> 3;
    int slot = ch & 7;
    soff2[it] = (slot ^ (row2[it] & 7)) << 3;
    dst0[it] = KV + ((it*256 + (tid & 0xC0)) << 3);
  }

  if (t0 < t1){
    int kv0 = t0 << 6;
#pragma unroll
    for (int it=0; it<2; ++it){
      gl_lds16(Kbase + (size_t)(kv0 + row2[it])*64 + soff2[it], dst0[it]);
      gl_lds16(Vbase + (size_t)row2[it]*T_ + kv0 + soff2[it], dst0[it] + 2*4096);
    }
  }
  __syncthreads();

  for (int t = t0; t < t1; ++t){
    int cur = (t - t0) & 1;
    int kv0 = t << 6;
    if (t + 1 < t1){
      int kvn = kv0 + 64;
      int nxt = cur ^ 1;
#pragma unroll
      for (int it=0; it<2; ++it){
        gl_lds16(Kbase + (size_t)(kvn + row2[it])*64 + soff2[it], dst0[it] + nxt*4096);
        gl_lds16(Vbase + (size_t)row2[it]*T_ + kvn + soff2[it], dst0[it] + (2+nxt)*4096);
      }
    }

    if (kv0 <= q0w + 31){   // wave-uniform: this wave has unmasked work
      const char* KsC = (const char*)(KV + cur*4096);
      const char* VsC = (const char*)(KV + (2+cur)*4096);

      f32x4 st[4][2];
#pragma unroll
      for (int kv=0;kv<4;++kv)
#pragma unroll
        for (int qs=0;qs<2;++qs) st[kv][qs] = z4;

#pragma unroll
      for (int ks=0;ks<2;++ks){
        short8 kf[4];
#pragma unroll
        for (int kv=0;kv<4;++kv){
          int row = kv*16 + c;
          kf[kv] = *(const short8*)(KsC + row*128 + (((ks*4+g) ^ (row&7)) << 4));
        }
#pragma unroll
        for (int kv=0;kv<4;++kv)
#pragma unroll
          for (int qs=0;qs<2;++qs)
            st[kv][qs] = __builtin_amdgcn_mfma_f32_16x16x32_bf16(kf[kv], qf[qs][ks], st[kv][qs], 0, 0, 0);
      }

      if (kv0 + 63 > q0w){  // diagonal tile: causal mask
#pragma unroll
        for (int kv=0;kv<4;++kv)
#pragma unroll
          for (int qs=0;qs<2;++qs)
#pragma unroll
            for (int r=0;r<4;++r){
              int kvi = kv0 + kv*16 + g*4 + r;
              int qi = q0w + qs*16 + c;
              if (kvi > qi) st[kv][qs][r] = -INFINITY;
            }
      }

#pragma unroll
      for (int qs=0;qs<2;++qs){
        float s01 = 0.f, s23 = 0.f;
#pragma unroll
        for (int kv=0;kv<4;++kv){
          float e0 = __builtin_amdgcn_exp2f(st[kv][qs][0]);
          float e1 = __builtin_amdgcn_exp2f(st[kv][qs][1]);
          float e2 = __builtin_amdgcn_exp2f(st[kv][qs][2]);
          float e3 = __builtin_amdgcn_exp2f(st[kv][qs][3]);
          st[kv][qs][0] = e0; st[kv][qs][1] = e1;
          st[kv][qs][2] = e2; st[kv][qs][3] = e3;
          s01 += e0 + e1; s23 += e2 + e3;
        }
        psum[qs] += s01 + s23;
        int q = qs*16 + c;
#pragma unroll
        for (int kv=0;kv<4;++kv){
          uint2v o;
          o.x = cvt_pk_bf16(st[kv][qs][0], st[kv][qs][1]);
          o.y = cvt_pk_bf16(st[kv][qs][2], st[kv][qs][3]);
          *(uint2v*)(PsB + q*128 + ((kv*32 + g*8) ^ ((q&7) << 4))) = o;
        }
      }

#pragma unroll
      for (int ks=0;ks<2;++ks){
        short8 vb[4];
#pragma unroll
        for (int ds=0;ds<4;++ds){
          int row = ds*16 + c;
          vb[ds] = *(const short8*)(VsC + row*128 + (((ks*4+g) ^ (row&7)) << 4));
        }
#pragma unroll
        for (int qs=0;qs<2;++qs){
          int q = qs*16 + c;
          short8 pa = *(const short8*)(PsB + q*128 + (((ks*4+g) << 4) ^ ((q&7) << 4)));
#pragma unroll
          for (int ds=0;ds<4;++ds)
            acc[qs][ds] = __builtin_amdgcn_mfma_f32_16x16x32_bf16(pa, vb[ds], acc[qs][ds], 0, 0, 0);
        }
      }
    }

    __syncthreads();
  }

#pragma unroll
  for (int qs=0;qs<2;++qs){
    psum[qs] += __shfl_xor(psum[qs], 16);
    psum[qs] += __shfl_xor(psum[qs], 32);
  }
  if (g == 0){
    lp[ck*65536 + bh*2048 + q0w + c]      = psum[0];
    lp[ck*65536 + bh*2048 + q0w + 16 + c] = psum[1];
  }
#pragma unroll
  for (int qs=0;qs<2;++qs){
#pragma unroll
    for (int r=0;r<4;++r){
      int trow = q0w + qs*16 + g*4 + r;
      size_t off = (((size_t)(ck*32 + bh)*2048) + trow)*64;
#pragma unroll
      for (int ds=0;ds<4;++ds)
        Pb[off + ds*16 + c] = f2bf(acc[qs][ds][r]);
    }
  }
}

// ---------------- merge partials: Y = (sum_ck P_ck)/(sum_ck l_ck), bf16 ----------------
__global__ void k_merge(const u16* __restrict__ Pb, const float* __restrict__ lp,
                        u16* __restrict__ Y)
{
  int idx = blockIdx.x * 256 + threadIdx.x;
  int d8 = idx & 7;
  int t  = (idx >> 3) & 2047;
  int bh = idx >> 14;
  int lt = bh*2048 + t;
  float l = lp[lt] + lp[lt + 65536] + lp[lt + 131072] + lp[lt + 196608];
  float inv = 1.0f / l;
  float s[8] = {0.f,0.f,0.f,0.f,0.f,0.f,0.f,0.f};
#pragma unroll
  for (int ck=0; ck<4; ++ck){
    short8 p = *(const short8*)(Pb + (((size_t)(ck*32 + bh)*2048 + t) << 6) + d8*8);
#pragma unroll
    for (int j=0;j<8;++j) s[j] += bf2f((u16)p[j]);
  }
  uint4v o;
  o.x = cvt_pk_bf16(s[0]*inv, s[1]*inv);
  o.y = cvt_pk_bf16(s[2]*inv, s[3]*inv);
  o.z = cvt_pk_bf16(s[4]*inv, s[5]*inv);
  o.w = cvt_pk_bf16(s[6]*inv, s[7]*inv);
  int bb = bh >> 4, hh = bh & 15;
  *(uint4v*)(Y + ((size_t)(bb*2048 + t))*1024 + hh*64 + d8*8) = o;
}

extern "C" void kernel_launch(void* const* d_in, const int* in_sizes, int n_in,
                              void* d_out, int out_size, void* d_ws, size_t ws_size,
                              hipStream_t stream)
{
  const float* x  = (const float*)d_in[0];
  const float* Wa = (const float*)d_in[1];
  const float* ba = (const float*)d_in[2];
  const float* Wp = (const float*)d_in[3];
  const float* bp = (const float*)d_in[4];
  float* out = (float*)d_out;
  char* ws = (char*)d_ws;

  // workspace layout (59 MB peak, lifetime-overlaid):
  //  phase1: xb [0,8) + WaT [8,14)    (dead after gemm0)
  //  attn:   Pb [0,32) bf16 partials [4][32][2048][64]
  //  [32,40) Qh   | after attn: Y (merge output)
  //  [40,48) Kh
  //  [48,56) Vt
  //  [56,58) WpT
  //  [58,59) lp f32 [4][32][2048]
  u16* xb  = (u16*)(ws);
  u16* WaT = (u16*)(ws + (8u  << 20));
  u16* Pb  = (u16*)(ws);
  u16* Qh  = (u16*)(ws + (32u << 20));
  u16* Y   = Qh;
  u16* Kh  = (u16*)(ws + (40u << 20));
  u16* Vt  = (u16*)(ws + (48u << 20));
  u16* WpT = (u16*)(ws + (56u << 20));
  float* lp = (float*)(ws + (58u << 20));

  k_conv<<<4096, 256, 0, stream>>>(x, xb);
  k_transpose<<<dim3(96,32), dim3(32,8), 0, stream>>>(Wa, WaT, 1024, 3072);
  k_transpose<<<dim3(32,32), dim3(32,8), 0, stream>>>(Wp, WpT, 1024, 1024);
  k_gemm0<<<768, 256, 0, stream>>>(xb, WaT, ba, Qh, Kh, Vt, 4096, 3072, 1024);
  k_attn<<<2048, 256, 0, stream>>>(Qh, Kh, Vt, Pb, lp);
  k_merge<<<2048, 256, 0, stream>>>(Pb, lp, Y);
  k_gemmp<<<256, 256, 0, stream>>>(Y, WpT, bp, out);
}

// Round 10
// 108.414 us; speedup vs baseline: 1.0804x; 1.0804x over previous
//
#include <hip/hip_runtime.h>

#define B_ 2
#define T_ 2048
#define C_ 1024
#define H_ 16
#define HD_ 64

typedef unsigned short u16;
typedef unsigned int u32;
typedef __attribute__((ext_vector_type(8))) short short8;
typedef __attribute__((ext_vector_type(4))) float f32x4;
typedef __attribute__((ext_vector_type(2))) u32 uint2v;
typedef __attribute__((ext_vector_type(4))) u32 uint4v;

typedef __attribute__((address_space(1))) const void* as1cv;
typedef __attribute__((address_space(3))) void* as3v;

__device__ __forceinline__ u16 f2bf(float x){
  union { float f; u32 u; } v; v.f = x;
  u32 r = v.u + 0x7fffu + ((v.u >> 16) & 1u);
  return (u16)(r >> 16);
}
__device__ __forceinline__ float bf2f(u16 h){
  union { u32 u; float f; } v; v.u = ((u32)h) << 16;
  return v.f;
}
// packed f32x2 -> bf16x2 (RTNE), single VALU inst
__device__ __forceinline__ u32 cvt_pk_bf16(float lo, float hi){
  u32 r;
  asm("v_cvt_pk_bf16_f32 %0, %1, %2" : "=v"(r) : "v"(lo), "v"(hi));
  return r;
}
__device__ __forceinline__ void gl_lds16(const u16* src, u16* dst){
  __builtin_amdgcn_global_load_lds((as1cv)src, (as3v)dst, 16, 0, 0);
}

// ---------------- f32 -> bf16 convert (x4 vectorized) ----------------
__global__ void k_conv(const float* __restrict__ in, u16* __restrict__ out){
  int i = blockIdx.x * 256 + threadIdx.x;
  f32x4 v = ((const f32x4*)in)[i];
  uint2v o;
  o.x = (u32)f2bf(v.x) | ((u32)f2bf(v.y) << 16);
  o.y = (u32)f2bf(v.z) | ((u32)f2bf(v.w) << 16);
  ((uint2v*)out)[i] = o;
}

// ------------- transpose + convert: out[c][r] = bf16(in[r][c]) -------------
__global__ void k_transpose(const float* __restrict__ in, u16* __restrict__ out,
                            int R, int Cc){
  __shared__ float tile[32][33];
  int c0 = blockIdx.x * 32, r0 = blockIdx.y * 32;
  int tx = threadIdx.x, ty = threadIdx.y;
#pragma unroll
  for (int ii = 0; ii < 4; ++ii)
    tile[ty + ii*8][tx] = in[(size_t)(r0 + ty + ii*8) * Cc + c0 + tx];
  __syncthreads();
#pragma unroll
  for (int ii = 0; ii < 4; ++ii)
    out[(size_t)(c0 + ty + ii*8) * R + r0 + tx] = f2bf(tile[tx][ty + ii*8]);
}

// ---------------- QKV GEMM + fused RoPE epilogue ----------------
// C[M=4096][N=3072] = A * Bt^T + bias.  BM=BN=128, BK=64, 4 waves.
// R8 single-buffer structure (stage -> sync -> compute -> sync): at 32KB LDS
// and 76 VGPR it runs 3 blocks/CU (launch_bounds(256,3)); grid 768 = exactly
// 3 blocks/CU, zero tail. Cross-block overlap hides the barrier drain (m114) —
// this beat the 64KB double-buffer which halved residency (R9 regression).
// Q cols (<1024):   RoPE + scale(0.125*log2e) -> Qh[bh][t][64] bf16
// K cols (1024..2048): RoPE -> Kh[bh][t][64] bf16
// V cols (>=2048):  transposed -> Vt[bh][d][t] bf16
__global__ __launch_bounds__(256, 3)
void k_gemm0(const u16* __restrict__ A, const u16* __restrict__ Bt,
             const float* __restrict__ bias, u16* __restrict__ Qh,
             u16* __restrict__ Kh, u16* __restrict__ vt,
             int M, int N, int K)
{
  __shared__ u16 As[128*64];
  __shared__ u16 Bs[128*64];
  int nwg = gridDim.x;
  int cpx = nwg >> 3;
  int bid = blockIdx.x;
  int wg = (bid & 7) * cpx + (bid >> 3);   // bijective XCD swizzle (nwg%8==0)
  int ntn = N >> 7;
  int m0 = (wg / ntn) << 7, n0 = (wg % ntn) << 7;
  int tid = threadIdx.x;
  int lane = tid & 63, w = tid >> 6;
  int c = lane & 15, g = lane >> 4;
  int wr = w >> 1, wc = w & 1;

  f32x4 z4 = {0.f,0.f,0.f,0.f};
  f32x4 acc[4][4];
#pragma unroll
  for (int i=0;i<4;++i)
#pragma unroll
    for (int j=0;j<4;++j) acc[i][j] = z4;

  u16* dstA = As + ((tid & 0xC0) << 3);
  u16* dstB = Bs + ((tid & 0xC0) << 3);

  for (int k0 = 0; k0 < K; k0 += 64){
#pragma unroll
    for (int it = 0; it < 4; ++it){
      int ch = it*256 + tid;
      int row = ch >> 3, slot = ch & 7;
      gl_lds16(A + (size_t)(m0+row)*K + k0 + slot*8, dstA + it*2048);
    }
#pragma unroll
    for (int it = 0; it < 4; ++it){
      int ch = it*256 + tid;
      int row = ch >> 3, slot = ch & 7;
      gl_lds16(Bt + (size_t)(n0+row)*K + k0 + slot*8, dstB + it*2048);
    }
    __syncthreads();
#pragma unroll
    for (int ks = 0; ks < 2; ++ks){
      short8 af[4], bf[4];
#pragma unroll
      for (int i=0;i<4;++i)
        af[i] = *(const short8*)(As + (wr*64 + i*16 + c)*64 + ks*32 + g*8);
#pragma unroll
      for (int j=0;j<4;++j)
        bf[j] = *(const short8*)(Bs + (wc*64 + j*16 + c)*64 + ks*32 + g*8);
#pragma unroll
      for (int i=0;i<4;++i)
#pragma unroll
        for (int j=0;j<4;++j)
          acc[i][j] = __builtin_amdgcn_mfma_f32_16x16x32_bf16(af[i], bf[j], acc[i][j], 0, 0, 0);
    }
    __syncthreads();
  }

  if (n0 >= 2048){
    // V section -> vt[bh][d][t], 4 consecutive t packed per 8B store
#pragma unroll
    for (int i=0;i<4;++i){
      int rowb = m0 + wr*64 + i*16 + g*4;
      int bb = rowb >> 11, t0 = rowb & 2047;
#pragma unroll
      for (int j=0;j<4;++j){
        int col = n0 + wc*64 + j*16 + c;
        float bv = bias[col];
        int vc = col - 2048;
        int hh = vc >> 6, d = vc & 63;
        uint2v o;
        o.x = (u32)f2bf(acc[i][j].x + bv) | ((u32)f2bf(acc[i][j].y + bv) << 16);
        o.y = (u32)f2bf(acc[i][j].z + bv) | ((u32)f2bf(acc[i][j].w + bv) << 16);
        *(uint2v*)(vt + ((size_t)((bb*16 + hh)*64 + d))*2048 + t0) = o;
      }
    }
  } else {
    // Q/K section: fused RoPE + head-split write
    bool isQ = (n0 < 1024);
    u16* dsth = isQ ? Qh : Kh;
    int colb = isQ ? n0 : (n0 - 1024);
    float qsc = isQ ? 0.180336880f : 1.0f;  // 0.125 * log2(e) on Q only
    float sgn = (c & 1) ? 1.f : -1.f;
#pragma unroll
    for (int nf=0; nf<4; ++nf){
      int scol = colb + wc*64 + nf*16 + c;
      int hh = scol >> 6, d = scol & 63;
      int ip = (d >> 1);
      float invr = exp2f((float)(-ip) * 0.4152410118609203f) * 0.15915494309f;
      float bv = bias[n0 + wc*64 + nf*16 + c];
      u16* base = dsth + (size_t)hh*2048*64 + d;
#pragma unroll
      for (int mf=0; mf<4; ++mf){
#pragma unroll
        for (int r=0; r<4; ++r){
          int row = m0 + wr*64 + mf*16 + g*4 + r;
          int t = row & 2047, b = row >> 11;
          float v = acc[mf][nf][r] + bv;
          float p = __shfl_xor(v, 1);
          float th = (float)t * invr;
          float fr = th - floorf(th);
          float sn = __builtin_amdgcn_sinf(fr);
          float cs = __builtin_amdgcn_cosf(fr);
          float y = (v*cs + p*sn*sgn) * qsc;
          base[((size_t)b*16*2048 + t)*64] = f2bf(y);
        }
      }
    }
  }
}

// ---------------- proj GEMM: out = Y * Wp^T + bias ----------------
// 128x128 tile, grid 256 (exactly 1 round), counted double-buffer loop.
__global__ __launch_bounds__(256, 2)
void k_gemmp(const u16* __restrict__ A, const u16* __restrict__ Bt,
             const float* __restrict__ bias, float* __restrict__ outf)
{
  __shared__ u16 LDSG[32768];              // [A0|A1|B0|B1]
  const int K = 1024, N = 1024;
  int nwg = gridDim.x;                     // 256
  int cpx = nwg >> 3;
  int bid = blockIdx.x;
  int wg = (bid & 7) * cpx + (bid >> 3);
  int m0 = (wg >> 3) << 7, n0 = (wg & 7) << 7;
  int tid = threadIdx.x;
  int lane = tid & 63, w = tid >> 6;
  int c = lane & 15, g = lane >> 4;
  int wr = w >> 1, wc = w & 1;

  f32x4 z4 = {0.f,0.f,0.f,0.f};
  f32x4 acc[4][4];
#pragma unroll
  for (int i=0;i<4;++i)
#pragma unroll
    for (int j=0;j<4;++j) acc[i][j] = z4;

  int rowS[4], slotS[4], dstS[4];
#pragma unroll
  for (int it=0; it<4; ++it){
    int ch = it*256 + tid;
    rowS[it] = ch >> 3;
    slotS[it] = (ch & 7) * 8;
    dstS[it] = it*2048 + ((tid & 0xC0) << 3);
  }
  const u16* Abase = A + (size_t)m0*K;
  const u16* Bbase = Bt + (size_t)n0*K;

#pragma unroll
  for (int it=0; it<4; ++it){
    gl_lds16(Abase + (size_t)rowS[it]*K + slotS[it], LDSG + dstS[it]);
    gl_lds16(Bbase + (size_t)rowS[it]*K + slotS[it], LDSG + 16384 + dstS[it]);
  }
  __syncthreads();

  const int nk = K >> 6;
  for (int kt = 0; kt < nk; ++kt){
    int cur = kt & 1;
    if (kt + 1 < nk){
      int k1 = (kt + 1) << 6;
      int nb = cur ^ 1;
#pragma unroll
      for (int it=0; it<4; ++it){
        gl_lds16(Abase + (size_t)rowS[it]*K + k1 + slotS[it], LDSG + nb*8192 + dstS[it]);
        gl_lds16(Bbase + (size_t)rowS[it]*K + k1 + slotS[it], LDSG + 16384 + nb*8192 + dstS[it]);
      }
    }
    const u16* As = LDSG + cur*8192;
    const u16* Bs = LDSG + 16384 + cur*8192;
#pragma unroll
    for (int ks = 0; ks < 2; ++ks){
      short8 af[4], bf[4];
#pragma unroll
      for (int i=0;i<4;++i)
        af[i] = *(const short8*)(As + (wr*64 + i*16 + c)*64 + ks*32 + g*8);
#pragma unroll
      for (int j=0;j<4;++j)
        bf[j] = *(const short8*)(Bs + (wc*64 + j*16 + c)*64 + ks*32 + g*8);
#pragma unroll
      for (int i=0;i<4;++i)
#pragma unroll
        for (int j=0;j<4;++j)
          acc[i][j] = __builtin_amdgcn_mfma_f32_16x16x32_bf16(af[i], bf[j], acc[i][j], 0, 0, 0);
    }
    __syncthreads();
  }

#pragma unroll
  for (int i=0;i<4;++i){
#pragma unroll
    for (int j=0;j<4;++j){
      int col = n0 + wc*64 + j*16 + c;
      float bv = bias[col];
#pragma unroll
      for (int r=0;r<4;++r){
        int row = m0 + wr*64 + i*16 + g*4 + r;
        outf[(size_t)row*N + col] = acc[i][j][r] + bv;
      }
    }
  }
}

// ---------------- causal flash attention, KV-split x4, 4-wave blocks ----------------
// Qh,Kh: [bh][t][64] bf16 (Q pre-scaled, log2 domain).  Vt: [bh][64][t] bf16.
// Grid: 2048 blocks of 256 threads (4 waves x 32 q-rows = 128 q-rows/block).
// FIXED-MAX softmax (m=0). Partials: bf16 O + f32 row sums; k_merge sums 4 chunks.
__global__ __launch_bounds__(256, 3)
void k_attn(const u16* __restrict__ Qh, const u16* __restrict__ Kh,
            const u16* __restrict__ Vt, u16* __restrict__ Pb,
            float* __restrict__ lp)
{
  __shared__ u16 KV[4*4096];     // [K0 | K1 | V0 | V1], XOR-swizzled 16B chunks
  __shared__ u16 Ps[4*32*64];    // per-wave P[q][kv], XOR-swizzled

  int bid = blockIdx.x;
  int qt = 15 - (bid >> 7);
  int r7 = bid & 127;
  int ck = r7 >> 5, bh = r7 & 31;
  int q0 = qt << 7;
  int tid = threadIdx.x, lane = tid & 63, w = tid >> 6;
  int c = lane & 15, g = lane >> 4;
  int q0w = q0 + w*32;
  int nt = (qt + 1) << 1;
  int t0 = (nt * ck) >> 2;
  int t1 = (nt * (ck + 1)) >> 2;

  const u16* Kbase = Kh + (size_t)bh * T_ * 64;
  const u16* Vbase = Vt + (size_t)bh * 64 * T_;
  const u16* Qbase = Qh + (size_t)bh * T_ * 64;

  short8 qf[2][2];
#pragma unroll
  for (int qs=0;qs<2;++qs)
#pragma unroll
    for (int ks=0;ks<2;++ks)
      qf[qs][ks] = *(const short8*)(Qbase + (size_t)(q0w + qs*16 + c)*64 + ks*32 + g*8);

  f32x4 z4 = {0.f,0.f,0.f,0.f};
  f32x4 acc[2][4];
#pragma unroll
  for (int qs=0;qs<2;++qs)
#pragma unroll
    for (int ds=0;ds<4;++ds) acc[qs][ds] = z4;
  float psum[2] = {0.f, 0.f};

  char* PsB = (char*)Ps + w*4096;

  int row2[2], soff2[2];
  u16* dst0[2];
#pragma unroll
  for (int it=0; it<2; ++it){
    int ch = it*256 + tid;
    row2[it] = ch >> 3;
    int slot = ch & 7;
    soff2[it] = (slot ^ (row2[it] & 7)) << 3;
    dst0[it] = KV + ((it*256 + (tid & 0xC0)) << 3);
  }

  if (t0 < t1){
    int kv0 = t0 << 6;
#pragma unroll
    for (int it=0; it<2; ++it){
      gl_lds16(Kbase + (size_t)(kv0 + row2[it])*64 + soff2[it], dst0[it]);
      gl_lds16(Vbase + (size_t)row2[it]*T_ + kv0 + soff2[it], dst0[it] + 2*4096);
    }
  }
  __syncthreads();

  for (int t = t0; t < t1; ++t){
    int cur = (t - t0) & 1;
    int kv0 = t << 6;
    if (t + 1 < t1){
      int kvn = kv0 + 64;
      int nxt = cur ^ 1;
#pragma unroll
      for (int it=0; it<2; ++it){
        gl_lds16(Kbase + (size_t)(kvn + row2[it])*64 + soff2[it], dst0[it] + nxt*4096);
        gl_lds16(Vbase + (size_t)row2[it]*T_ + kvn + soff2[it], dst0[it] + (2+nxt)*4096);
      }
    }

    if (kv0 <= q0w + 31){   // wave-uniform: this wave has unmasked work
      const char* KsC = (const char*)(KV + cur*4096);
      const char* VsC = (const char*)(KV + (2+cur)*4096);

      f32x4 st[4][2];
#pragma unroll
      for (int kv=0;kv<4;++kv)
#pragma unroll
        for (int qs=0;qs<2;++qs) st[kv][qs] = z4;

#pragma unroll
      for (int ks=0;ks<2;++ks){
        short8 kf[4];
#pragma unroll
        for (int kv=0;kv<4;++kv){
          int row = kv*16 + c;
          kf[kv] = *(const short8*)(KsC + row*128 + (((ks*4+g) ^ (row&7)) << 4));
        }
#pragma unroll
        for (int kv=0;kv<4;++kv)
#pragma unroll
          for (int qs=0;qs<2;++qs)
            st[kv][qs] = __builtin_amdgcn_mfma_f32_16x16x32_bf16(kf[kv], qf[qs][ks], st[kv][qs], 0, 0, 0);
      }

      if (kv0 + 63 > q0w){  // diagonal tile: causal mask
#pragma unroll
        for (int kv=0;kv<4;++kv)
#pragma unroll
          for (int qs=0;qs<2;++qs)
#pragma unroll
            for (int r=0;r<4;++r){
              int kvi = kv0 + kv*16 + g*4 + r;
              int qi = q0w + qs*16 + c;
              if (kvi > qi) st[kv][qs][r] = -INFINITY;
            }
      }

#pragma unroll
      for (int qs=0;qs<2;++qs){
        float s01 = 0.f, s23 = 0.f;
#pragma unroll
        for (int kv=0;kv<4;++kv){
          float e0 = __builtin_amdgcn_exp2f(st[kv][qs][0]);
          float e1 = __builtin_amdgcn_exp2f(st[kv][qs][1]);
          float e2 = __builtin_amdgcn_exp2f(st[kv][qs][2]);
          float e3 = __builtin_amdgcn_exp2f(st[kv][qs][3]);
          st[kv][qs][0] = e0; st[kv][qs][1] = e1;
          st[kv][qs][2] = e2; st[kv][qs][3] = e3;
          s01 += e0 + e1; s23 += e2 + e3;
        }
        psum[qs] += s01 + s23;
        int q = qs*16 + c;
#pragma unroll
        for (int kv=0;kv<4;++kv){
          uint2v o;
          o.x = cvt_pk_bf16(st[kv][qs][0], st[kv][qs][1]);
          o.y = cvt_pk_bf16(st[kv][qs][2], st[kv][qs][3]);
          *(uint2v*)(PsB + q*128 + ((kv*32 + g*8) ^ ((q&7) << 4))) = o;
        }
      }

#pragma unroll
      for (int ks=0;ks<2;++ks){
        short8 vb[4];
#pragma unroll
        for (int ds=0;ds<4;++ds){
          int row = ds*16 + c;
          vb[ds] = *(const short8*)(VsC + row*128 + (((ks*4+g) ^ (row&7)) << 4));
        }
#pragma unroll
        for (int qs=0;qs<2;++qs){
          int q = qs*16 + c;
          short8 pa = *(const short8*)(PsB + q*128 + (((ks*4+g) << 4) ^ ((q&7) << 4)));
#pragma unroll
          for (int ds=0;ds<4;++ds)
            acc[qs][ds] = __builtin_amdgcn_mfma_f32_16x16x32_bf16(pa, vb[ds], acc[qs][ds], 0, 0, 0);
        }
      }
    }

    __syncthreads();
  }

#pragma unroll
  for (int qs=0;qs<2;++qs){
    psum[qs] += __shfl_xor(psum[qs], 16);
    psum[qs] += __shfl_xor(psum[qs], 32);
  }
  if (g == 0){
    lp[ck*65536 + bh*2048 + q0w + c]      = psum[0];
    lp[ck*65536 + bh*2048 + q0w + 16 + c] = psum[1];
  }
#pragma unroll
  for (int qs=0;qs<2;++qs){
#pragma unroll
    for (int r=0;r<4;++r){
      int trow = q0w + qs*16 + g*4 + r;
      size_t off = (((size_t)(ck*32 + bh)*2048) + trow)*64;
#pragma unroll
      for (int ds=0;ds<4;++ds)
        Pb[off + ds*16 + c] = f2bf(acc[qs][ds][r]);
    }
  }
}

// ---------------- merge partials: Y = (sum_ck P_ck)/(sum_ck l_ck), bf16 ----------------
__global__ void k_merge(const u16* __restrict__ Pb, const float* __restrict__ lp,
                        u16* __restrict__ Y)
{
  int idx = blockIdx.x * 256 + threadIdx.x;
  int d8 = idx & 7;
  int t  = (idx >> 3) & 2047;
  int bh = idx >> 14;
  int lt = bh*2048 + t;
  float l = lp[lt] + lp[lt + 65536] + lp[lt + 131072] + lp[lt + 196608];
  float inv = 1.0f / l;
  float s[8] = {0.f,0.f,0.f,0.f,0.f,0.f,0.f,0.f};
#pragma unroll
  for (int ck=0; ck<4; ++ck){
    short8 p = *(const short8*)(Pb + (((size_t)(ck*32 + bh)*2048 + t) << 6) + d8*8);
#pragma unroll
    for (int j=0;j<8;++j) s[j] += bf2f((u16)p[j]);
  }
  uint4v o;
  o.x = cvt_pk_bf16(s[0]*inv, s[1]*inv);
  o.y = cvt_pk_bf16(s[2]*inv, s[3]*inv);
  o.z = cvt_pk_bf16(s[4]*inv, s[5]*inv);
  o.w = cvt_pk_bf16(s[6]*inv, s[7]*inv);
  int bb = bh >> 4, hh = bh & 15;
  *(uint4v*)(Y + ((size_t)(bb*2048 + t))*1024 + hh*64 + d8*8) = o;
}

extern "C" void kernel_launch(void* const* d_in, const int* in_sizes, int n_in,
                              void* d_out, int out_size, void* d_ws, size_t ws_size,
                              hipStream_t stream)
{
  const float* x  = (const float*)d_in[0];
  const float* Wa = (const float*)d_in[1];
  const float* ba = (const float*)d_in[2];
  const float* Wp = (const float*)d_in[3];
  const float* bp = (const float*)d_in[4];
  float* out = (float*)d_out;
  char* ws = (char*)d_ws;

  // workspace layout (59 MB peak, lifetime-overlaid):
  //  phase1: xb [0,8) + WaT [8,14)    (dead after gemm0)
  //  attn:   Pb [0,32) bf16 partials [4][32][2048][64]
  //  [32,40) Qh   | after attn: Y (merge output)
  //  [40,48) Kh
  //  [48,56) Vt
  //  [56,58) WpT
  //  [58,59) lp f32 [4][32][2048]
  u16* xb  = (u16*)(ws);
  u16* WaT = (u16*)(ws + (8u  << 20));
  u16* Pb  = (u16*)(ws);
  u16* Qh  = (u16*)(ws + (32u << 20));
  u16* Y   = Qh;
  u16* Kh  = (u16*)(ws + (40u << 20));
  u16* Vt  = (u16*)(ws + (48u << 20));
  u16* WpT = (u16*)(ws + (56u << 20));
  float* lp = (float*)(ws + (58u << 20));

  k_conv<<<4096, 256, 0, stream>>>(x, xb);
  k_transpose<<<dim3(96,32), dim3(32,8), 0, stream>>>(Wa, WaT, 1024, 3072);
  k_transpose<<<dim3(32,32), dim3(32,8), 0, stream>>>(Wp, WpT, 1024, 1024);
  k_gemm0<<<768, 256, 0, stream>>>(xb, WaT, ba, Qh, Kh, Vt, 4096, 3072, 1024);
  k_attn<<<2048, 256, 0, stream>>>(Qh, Kh, Vt, Pb, lp);
  k_merge<<<2048, 256, 0, stream>>>(Pb, lp, Y);
  k_gemmp<<<256, 256, 0, stream>>>(Y, WpT, bp, out);
}

// Round 11
// 107.260 us; speedup vs baseline: 1.0921x; 1.0108x over previous
//
#include <hip/hip_runtime.h>

#define B_ 2
#define T_ 2048
#define C_ 1024
#define H_ 16
#define HD_ 64

typedef unsigned short u16;
typedef unsigned int u32;
typedef __attribute__((ext_vector_type(8))) short short8;
typedef __attribute__((ext_vector_type(4))) float f32x4;
typedef __attribute__((ext_vector_type(2))) u32 uint2v;
typedef __attribute__((ext_vector_type(4))) u32 uint4v;

typedef __attribute__((address_space(1))) const void* as1cv;
typedef __attribute__((address_space(3))) void* as3v;

__device__ __forceinline__ u16 f2bf(float x){
  union { float f; u32 u; } v; v.f = x;
  u32 r = v.u + 0x7fffu + ((v.u >> 16) & 1u);
  return (u16)(r >> 16);
}
__device__ __forceinline__ float bf2f(u16 h){
  union { u32 u; float f; } v; v.u = ((u32)h) << 16;
  return v.f;
}
// packed f32x2 -> bf16x2 (RTNE), single VALU inst
__device__ __forceinline__ u32 cvt_pk_bf16(float lo, float hi){
  u32 r;
  asm("v_cvt_pk_bf16_f32 %0, %1, %2" : "=v"(r) : "v"(lo), "v"(hi));
  return r;
}
__device__ __forceinline__ void gl_lds16(const u16* src, u16* dst){
  __builtin_amdgcn_global_load_lds((as1cv)src, (as3v)dst, 16, 0, 0);
}

// ---------------- f32 -> bf16 convert (x4 vectorized) ----------------
__global__ void k_conv(const float* __restrict__ in, u16* __restrict__ out){
  int i = blockIdx.x * 256 + threadIdx.x;
  f32x4 v = ((const f32x4*)in)[i];
  uint2v o;
  o.x = (u32)f2bf(v.x) | ((u32)f2bf(v.y) << 16);
  o.y = (u32)f2bf(v.z) | ((u32)f2bf(v.w) << 16);
  ((uint2v*)out)[i] = o;
}

// ------------- transpose + convert: out[c][r] = bf16(in[r][c]) -------------
__global__ void k_transpose(const float* __restrict__ in, u16* __restrict__ out,
                            int R, int Cc){
  __shared__ float tile[32][33];
  int c0 = blockIdx.x * 32, r0 = blockIdx.y * 32;
  int tx = threadIdx.x, ty = threadIdx.y;
#pragma unroll
  for (int ii = 0; ii < 4; ++ii)
    tile[ty + ii*8][tx] = in[(size_t)(r0 + ty + ii*8) * Cc + c0 + tx];
  __syncthreads();
#pragma unroll
  for (int ii = 0; ii < 4; ++ii)
    out[(size_t)(c0 + ty + ii*8) * R + r0 + tx] = f2bf(tile[tx][ty + ii*8]);
}

// ---------------- QKV GEMM + fused RoPE epilogue (unchanged from R10) ----------------
__global__ __launch_bounds__(256, 3)
void k_gemm0(const u16* __restrict__ A, const u16* __restrict__ Bt,
             const float* __restrict__ bias, u16* __restrict__ Qh,
             u16* __restrict__ Kh, u16* __restrict__ vt,
             int M, int N, int K)
{
  __shared__ u16 As[128*64];
  __shared__ u16 Bs[128*64];
  int nwg = gridDim.x;
  int cpx = nwg >> 3;
  int bid = blockIdx.x;
  int wg = (bid & 7) * cpx + (bid >> 3);   // bijective XCD swizzle (nwg%8==0)
  int ntn = N >> 7;
  int m0 = (wg / ntn) << 7, n0 = (wg % ntn) << 7;
  int tid = threadIdx.x;
  int lane = tid & 63, w = tid >> 6;
  int c = lane & 15, g = lane >> 4;
  int wr = w >> 1, wc = w & 1;

  f32x4 z4 = {0.f,0.f,0.f,0.f};
  f32x4 acc[4][4];
#pragma unroll
  for (int i=0;i<4;++i)
#pragma unroll
    for (int j=0;j<4;++j) acc[i][j] = z4;

  u16* dstA = As + ((tid & 0xC0) << 3);
  u16* dstB = Bs + ((tid & 0xC0) << 3);

  for (int k0 = 0; k0 < K; k0 += 64){
#pragma unroll
    for (int it = 0; it < 4; ++it){
      int ch = it*256 + tid;
      int row = ch >> 3, slot = ch & 7;
      gl_lds16(A + (size_t)(m0+row)*K + k0 + slot*8, dstA + it*2048);
    }
#pragma unroll
    for (int it = 0; it < 4; ++it){
      int ch = it*256 + tid;
      int row = ch >> 3, slot = ch & 7;
      gl_lds16(Bt + (size_t)(n0+row)*K + k0 + slot*8, dstB + it*2048);
    }
    __syncthreads();
#pragma unroll
    for (int ks = 0; ks < 2; ++ks){
      short8 af[4], bf[4];
#pragma unroll
      for (int i=0;i<4;++i)
        af[i] = *(const short8*)(As + (wr*64 + i*16 + c)*64 + ks*32 + g*8);
#pragma unroll
      for (int j=0;j<4;++j)
        bf[j] = *(const short8*)(Bs + (wc*64 + j*16 + c)*64 + ks*32 + g*8);
#pragma unroll
      for (int i=0;i<4;++i)
#pragma unroll
        for (int j=0;j<4;++j)
          acc[i][j] = __builtin_amdgcn_mfma_f32_16x16x32_bf16(af[i], bf[j], acc[i][j], 0, 0, 0);
    }
    __syncthreads();
  }

  if (n0 >= 2048){
    // V section -> vt[bh][d][t], 4 consecutive t packed per 8B store
#pragma unroll
    for (int i=0;i<4;++i){
      int rowb = m0 + wr*64 + i*16 + g*4;
      int bb = rowb >> 11, t0 = rowb & 2047;
#pragma unroll
      for (int j=0;j<4;++j){
        int col = n0 + wc*64 + j*16 + c;
        float bv = bias[col];
        int vc = col - 2048;
        int hh = vc >> 6, d = vc & 63;
        uint2v o;
        o.x = (u32)f2bf(acc[i][j].x + bv) | ((u32)f2bf(acc[i][j].y + bv) << 16);
        o.y = (u32)f2bf(acc[i][j].z + bv) | ((u32)f2bf(acc[i][j].w + bv) << 16);
        *(uint2v*)(vt + ((size_t)((bb*16 + hh)*64 + d))*2048 + t0) = o;
      }
    }
  } else {
    // Q/K section: fused RoPE + head-split write
    bool isQ = (n0 < 1024);
    u16* dsth = isQ ? Qh : Kh;
    int colb = isQ ? n0 : (n0 - 1024);
    float qsc = isQ ? 0.180336880f : 1.0f;  // 0.125 * log2(e) on Q only
    float sgn = (c & 1) ? 1.f : -1.f;
#pragma unroll
    for (int nf=0; nf<4; ++nf){
      int scol = colb + wc*64 + nf*16 + c;
      int hh = scol >> 6, d = scol & 63;
      int ip = (d >> 1);
      float invr = exp2f((float)(-ip) * 0.4152410118609203f) * 0.15915494309f;
      float bv = bias[n0 + wc*64 + nf*16 + c];
      u16* base = dsth + (size_t)hh*2048*64 + d;
#pragma unroll
      for (int mf=0; mf<4; ++mf){
#pragma unroll
        for (int r=0; r<4; ++r){
          int row = m0 + wr*64 + mf*16 + g*4 + r;
          int t = row & 2047, b = row >> 11;
          float v = acc[mf][nf][r] + bv;
          float p = __shfl_xor(v, 1);
          float th = (float)t * invr;
          float fr = th - floorf(th);
          float sn = __builtin_amdgcn_sinf(fr);
          float cs = __builtin_amdgcn_cosf(fr);
          float y = (v*cs + p*sn*sgn) * qsc;
          base[((size_t)b*16*2048 + t)*64] = f2bf(y);
        }
      }
    }
  }
}

// ---------------- proj GEMM: out = Y * Wp^T + bias ----------------
// 64x128 tile, grid 512 (2 blocks/CU, all resident), double-buffered,
// 48 KB LDS -> 3-resident capacity; cross-block overlap + in-block dbuf.
__global__ __launch_bounds__(256, 3)
void k_gemmp(const u16* __restrict__ A, const u16* __restrict__ Bt,
             const float* __restrict__ bias, float* __restrict__ outf)
{
  __shared__ u16 LDSG[24576];     // A0@0 A1@4096 | B0@8192 B1@16384 (u16 idx)
  const int K = 1024, N = 1024;
  int nwg = gridDim.x;            // 512
  int cpx = nwg >> 3;
  int bid = blockIdx.x;
  int wg = (bid & 7) * cpx + (bid >> 3);
  int m0 = (wg >> 3) << 6, n0 = (wg & 7) << 7;
  int tid = threadIdx.x;
  int lane = tid & 63, w = tid >> 6;
  int c = lane & 15, g = lane >> 4;
  int wr = w >> 1, wc = w & 1;

  f32x4 z4 = {0.f,0.f,0.f,0.f};
  f32x4 acc[2][4];
#pragma unroll
  for (int i=0;i<2;++i)
#pragma unroll
    for (int j=0;j<4;++j) acc[i][j] = z4;

  int rowA[2], slotA[2], dstA[2];
#pragma unroll
  for (int it=0; it<2; ++it){
    int ch = it*256 + tid;
    rowA[it] = ch >> 3;
    slotA[it] = (ch & 7) * 8;
    dstA[it] = it*2048 + ((tid & 0xC0) << 3);
  }
  int rowB[4], slotB[4], dstB[4];
#pragma unroll
  for (int it=0; it<4; ++it){
    int ch = it*256 + tid;
    rowB[it] = ch >> 3;
    slotB[it] = (ch & 7) * 8;
    dstB[it] = 8192 + it*2048 + ((tid & 0xC0) << 3);
  }
  const u16* Abase = A + (size_t)m0*K;
  const u16* Bbase = Bt + (size_t)n0*K;

  // prologue: stage K-tile 0 into buf 0
#pragma unroll
  for (int it=0; it<2; ++it)
    gl_lds16(Abase + (size_t)rowA[it]*K + slotA[it], LDSG + dstA[it]);
#pragma unroll
  for (int it=0; it<4; ++it)
    gl_lds16(Bbase + (size_t)rowB[it]*K + slotB[it], LDSG + dstB[it]);
  __syncthreads();

  const int nk = K >> 6;
  for (int kt = 0; kt < nk; ++kt){
    int cur = kt & 1;
    if (kt + 1 < nk){
      int k1 = (kt + 1) << 6;
      int nb = cur ^ 1;
#pragma unroll
      for (int it=0; it<2; ++it)
        gl_lds16(Abase + (size_t)rowA[it]*K + k1 + slotA[it], LDSG + nb*4096 + dstA[it]);
#pragma unroll
      for (int it=0; it<4; ++it)
        gl_lds16(Bbase + (size_t)rowB[it]*K + k1 + slotB[it], LDSG + nb*8192 + dstB[it]);
    }
    const u16* As = LDSG + cur*4096;
    const u16* Bs = LDSG + 8192 + cur*8192;
#pragma unroll
    for (int ks = 0; ks < 2; ++ks){
      short8 af[2], bf[4];
#pragma unroll
      for (int i=0;i<2;++i)
        af[i] = *(const short8*)(As + (wr*32 + i*16 + c)*64 + ks*32 + g*8);
#pragma unroll
      for (int j=0;j<4;++j)
        bf[j] = *(const short8*)(Bs + (wc*64 + j*16 + c)*64 + ks*32 + g*8);
#pragma unroll
      for (int i=0;i<2;++i)
#pragma unroll
        for (int j=0;j<4;++j)
          acc[i][j] = __builtin_amdgcn_mfma_f32_16x16x32_bf16(af[i], bf[j], acc[i][j], 0, 0, 0);
    }
    __syncthreads();
  }

#pragma unroll
  for (int i=0;i<2;++i){
#pragma unroll
    for (int j=0;j<4;++j){
      int col = n0 + wc*64 + j*16 + c;
      float bv = bias[col];
#pragma unroll
      for (int r=0;r<4;++r){
        int row = m0 + wr*32 + i*16 + g*4 + r;
        outf[(size_t)row*N + col] = acc[i][j][r] + bv;
      }
    }
  }
}

// ---------------- causal flash attention, ADAPTIVE KV-split ----------------
// Split factor per q-tile: qt>=4 -> 4 chunks, qt 1..3 -> 2, qt 0 -> 1.
// Chunk lengths are monotone-decreasing in dispatch order (8..1 tiles):
//   bid <1536: qt = 15-(bid>>7), ck=(bid>>5)&3, bh=bid&31      (split 4)
//   <1728:     x=bid-1536; qt = 3-(x>>6), ck=(x>>5)&1, bh=x&31 (split 2)
//   <1760:     qt = 0, ck = 0, bh = (bid-1728)&31              (split 1)
// FIXED-MAX softmax (m=0). Partials: bf16 O + f32 row sums; k_merge sums nsp chunks.
__global__ __launch_bounds__(256, 3)
void k_attn(const u16* __restrict__ Qh, const u16* __restrict__ Kh,
            const u16* __restrict__ Vt, u16* __restrict__ Pb,
            float* __restrict__ lp)
{
  __shared__ u16 KV[4*4096];     // [K0 | K1 | V0 | V1], XOR-swizzled 16B chunks
  __shared__ u16 Ps[4*32*64];    // per-wave P[q][kv], XOR-swizzled

  int bid = blockIdx.x;
  int qt, ck, bh, l2nsp;
  if (bid < 1536){
    qt = 15 - (bid >> 7); ck = (bid >> 5) & 3; bh = bid & 31; l2nsp = 2;
  } else if (bid < 1728){
    int x = bid - 1536;
    qt = 3 - (x >> 6); ck = (x >> 5) & 1; bh = x & 31; l2nsp = 1;
  } else {
    qt = 0; ck = 0; bh = (bid - 1728) & 31; l2nsp = 0;
  }
  int q0 = qt << 7;
  int tid = threadIdx.x, lane = tid & 63, w = tid >> 6;
  int c = lane & 15, g = lane >> 4;
  int q0w = q0 + w*32;
  int nt = (qt + 1) << 1;
  int t0 = (nt * ck) >> l2nsp;
  int t1 = (nt * (ck + 1)) >> l2nsp;

  const u16* Kbase = Kh + (size_t)bh * T_ * 64;
  const u16* Vbase = Vt + (size_t)bh * 64 * T_;
  const u16* Qbase = Qh + (size_t)bh * T_ * 64;

  short8 qf[2][2];
#pragma unroll
  for (int qs=0;qs<2;++qs)
#pragma unroll
    for (int ks=0;ks<2;++ks)
      qf[qs][ks] = *(const short8*)(Qbase + (size_t)(q0w + qs*16 + c)*64 + ks*32 + g*8);

  f32x4 z4 = {0.f,0.f,0.f,0.f};
  f32x4 acc[2][4];
#pragma unroll
  for (int qs=0;qs<2;++qs)
#pragma unroll
    for (int ds=0;ds<4;++ds) acc[qs][ds] = z4;
  float psum[2] = {0.f, 0.f};

  char* PsB = (char*)Ps + w*4096;

  int row2[2], soff2[2];
  u16* dst0[2];
#pragma unroll
  for (int it=0; it<2; ++it){
    int ch = it*256 + tid;
    row2[it] = ch >> 3;
    int slot = ch & 7;
    soff2[it] = (slot ^ (row2[it] & 7)) << 3;
    dst0[it] = KV + ((it*256 + (tid & 0xC0)) << 3);
  }

  {
    int kv0 = t0 << 6;
#pragma unroll
    for (int it=0; it<2; ++it){
      gl_lds16(Kbase + (size_t)(kv0 + row2[it])*64 + soff2[it], dst0[it]);
      gl_lds16(Vbase + (size_t)row2[it]*T_ + kv0 + soff2[it], dst0[it] + 2*4096);
    }
  }
  __syncthreads();

  for (int t = t0; t < t1; ++t){
    int cur = (t - t0) & 1;
    int kv0 = t << 6;
    if (t + 1 < t1){
      int kvn = kv0 + 64;
      int nxt = cur ^ 1;
#pragma unroll
      for (int it=0; it<2; ++it){
        gl_lds16(Kbase + (size_t)(kvn + row2[it])*64 + soff2[it], dst0[it] + nxt*4096);
        gl_lds16(Vbase + (size_t)row2[it]*T_ + kvn + soff2[it], dst0[it] + (2+nxt)*4096);
      }
    }

    if (kv0 <= q0w + 31){   // wave-uniform: this wave has unmasked work
      const char* KsC = (const char*)(KV + cur*4096);
      const char* VsC = (const char*)(KV + (2+cur)*4096);

      f32x4 st[4][2];
#pragma unroll
      for (int kv=0;kv<4;++kv)
#pragma unroll
        for (int qs=0;qs<2;++qs) st[kv][qs] = z4;

#pragma unroll
      for (int ks=0;ks<2;++ks){
        short8 kf[4];
#pragma unroll
        for (int kv=0;kv<4;++kv){
          int row = kv*16 + c;
          kf[kv] = *(const short8*)(KsC + row*128 + (((ks*4+g) ^ (row&7)) << 4));
        }
#pragma unroll
        for (int kv=0;kv<4;++kv)
#pragma unroll
          for (int qs=0;qs<2;++qs)
            st[kv][qs] = __builtin_amdgcn_mfma_f32_16x16x32_bf16(kf[kv], qf[qs][ks], st[kv][qs], 0, 0, 0);
      }

      if (kv0 + 63 > q0w){  // diagonal tile: causal mask
#pragma unroll
        for (int kv=0;kv<4;++kv)
#pragma unroll
          for (int qs=0;qs<2;++qs)
#pragma unroll
            for (int r=0;r<4;++r){
              int kvi = kv0 + kv*16 + g*4 + r;
              int qi = q0w + qs*16 + c;
              if (kvi > qi) st[kv][qs][r] = -INFINITY;
            }
      }

#pragma unroll
      for (int qs=0;qs<2;++qs){
        float s01 = 0.f, s23 = 0.f;
#pragma unroll
        for (int kv=0;kv<4;++kv){
          float e0 = __builtin_amdgcn_exp2f(st[kv][qs][0]);
          float e1 = __builtin_amdgcn_exp2f(st[kv][qs][1]);
          float e2 = __builtin_amdgcn_exp2f(st[kv][qs][2]);
          float e3 = __builtin_amdgcn_exp2f(st[kv][qs][3]);
          st[kv][qs][0] = e0; st[kv][qs][1] = e1;
          st[kv][qs][2] = e2; st[kv][qs][3] = e3;
          s01 += e0 + e1; s23 += e2 + e3;
        }
        psum[qs] += s01 + s23;
        int q = qs*16 + c;
#pragma unroll
        for (int kv=0;kv<4;++kv){
          uint2v o;
          o.x = cvt_pk_bf16(st[kv][qs][0], st[kv][qs][1]);
          o.y = cvt_pk_bf16(st[kv][qs][2], st[kv][qs][3]);
          *(uint2v*)(PsB + q*128 + ((kv*32 + g*8) ^ ((q&7) << 4))) = o;
        }
      }

#pragma unroll
      for (int ks=0;ks<2;++ks){
        short8 vb[4];
#pragma unroll
        for (int ds=0;ds<4;++ds){
          int row = ds*16 + c;
          vb[ds] = *(const short8*)(VsC + row*128 + (((ks*4+g) ^ (row&7)) << 4));
        }
#pragma unroll
        for (int qs=0;qs<2;++qs){
          int q = qs*16 + c;
          short8 pa = *(const short8*)(PsB + q*128 + (((ks*4+g) << 4) ^ ((q&7) << 4)));
#pragma unroll
          for (int ds=0;ds<4;++ds)
            acc[qs][ds] = __builtin_amdgcn_mfma_f32_16x16x32_bf16(pa, vb[ds], acc[qs][ds], 0, 0, 0);
        }
      }
    }

    __syncthreads();
  }

#pragma unroll
  for (int qs=0;qs<2;++qs){
    psum[qs] += __shfl_xor(psum[qs], 16);
    psum[qs] += __shfl_xor(psum[qs], 32);
  }
  if (g == 0){
    lp[ck*65536 + bh*2048 + q0w + c]      = psum[0];
    lp[ck*65536 + bh*2048 + q0w + 16 + c] = psum[1];
  }
#pragma unroll
  for (int qs=0;qs<2;++qs){
#pragma unroll
    for (int r=0;r<4;++r){
      int trow = q0w + qs*16 + g*4 + r;
      size_t off = (((size_t)(ck*32 + bh)*2048) + trow)*64;
#pragma unroll
      for (int ds=0;ds<4;++ds)
        Pb[off + ds*16 + c] = f2bf(acc[qs][ds][r]);
    }
  }
}

// ---------------- merge partials (variable split count per qt) ----------------
__global__ void k_merge(const u16* __restrict__ Pb, const float* __restrict__ lp,
                        u16* __restrict__ Y)
{
  int idx = blockIdx.x * 256 + threadIdx.x;
  int d8 = idx & 7;
  int t  = (idx >> 3) & 2047;
  int bh = idx >> 14;
  int qt = t >> 7;
  int lt = bh*2048 + t;
  float s[8];
  float l = lp[lt];
  {
    short8 p = *(const short8*)(Pb + (((size_t)bh*2048 + t) << 6) + d8*8);
#pragma unroll
    for (int j=0;j<8;++j) s[j] = bf2f((u16)p[j]);
  }
  if (qt >= 1){
    l += lp[lt + 65536];
    short8 p = *(const short8*)(Pb + (((size_t)(32 + bh)*2048 + t) << 6) + d8*8);
#pragma unroll
    for (int j=0;j<8;++j) s[j] += bf2f((u16)p[j]);
  }
  if (qt >= 4){
    l += lp[lt + 131072] + lp[lt + 196608];
    short8 p2 = *(const short8*)(Pb + (((size_t)(64 + bh)*2048 + t) << 6) + d8*8);
    short8 p3 = *(const short8*)(Pb + (((size_t)(96 + bh)*2048 + t) << 6) + d8*8);
#pragma unroll
    for (int j=0;j<8;++j) s[j] += bf2f((u16)p2[j]) + bf2f((u16)p3[j]);
  }
  float inv = 1.0f / l;
  uint4v o;
  o.x = cvt_pk_bf16(s[0]*inv, s[1]*inv);
  o.y = cvt_pk_bf16(s[2]*inv, s[3]*inv);
  o.z = cvt_pk_bf16(s[4]*inv, s[5]*inv);
  o.w = cvt_pk_bf16(s[6]*inv, s[7]*inv);
  int bb = bh >> 4, hh = bh & 15;
  *(uint4v*)(Y + ((size_t)(bb*2048 + t))*1024 + hh*64 + d8*8) = o;
}

extern "C" void kernel_launch(void* const* d_in, const int* in_sizes, int n_in,
                              void* d_out, int out_size, void* d_ws, size_t ws_size,
                              hipStream_t stream)
{
  const float* x  = (const float*)d_in[0];
  const float* Wa = (const float*)d_in[1];
  const float* ba = (const float*)d_in[2];
  const float* Wp = (const float*)d_in[3];
  const float* bp = (const float*)d_in[4];
  float* out = (float*)d_out;
  char* ws = (char*)d_ws;

  // workspace layout (59 MB peak, lifetime-overlaid):
  //  phase1: xb [0,8) + WaT [8,14)    (dead after gemm0)
  //  attn:   Pb [0,32) bf16 partials [4][32][2048][64] (slots per qt's nsp)
  //  [32,40) Qh   | after attn: Y (merge output)
  //  [40,48) Kh
  //  [48,56) Vt
  //  [56,58) WpT
  //  [58,59) lp f32 [4][32][2048]
  u16* xb  = (u16*)(ws);
  u16* WaT = (u16*)(ws + (8u  << 20));
  u16* Pb  = (u16*)(ws);
  u16* Qh  = (u16*)(ws + (32u << 20));
  u16* Y   = Qh;
  u16* Kh  = (u16*)(ws + (40u << 20));
  u16* Vt  = (u16*)(ws + (48u << 20));
  u16* WpT = (u16*)(ws + (56u << 20));
  float* lp = (float*)(ws + (58u << 20));

  k_conv<<<4096, 256, 0, stream>>>(x, xb);
  k_transpose<<<dim3(96,32), dim3(32,8), 0, stream>>>(Wa, WaT, 1024, 3072);
  k_transpose<<<dim3(32,32), dim3(32,8), 0, stream>>>(Wp, WpT, 1024, 1024);
  k_gemm0<<<768, 256, 0, stream>>>(xb, WaT, ba, Qh, Kh, Vt, 4096, 3072, 1024);
  k_attn<<<1760, 256, 0, stream>>>(Qh, Kh, Vt, Pb, lp);
  k_merge<<<2048, 256, 0, stream>>>(Pb, lp, Y);
  k_gemmp<<<512, 256, 0, stream>>>(Y, WpT, bp, out);
}

// Round 12
// 99.038 us; speedup vs baseline: 1.1827x; 1.0830x over previous
//
#include <hip/hip_runtime.h>

#define B_ 2
#define T_ 2048
#define C_ 1024
#define H_ 16
#define HD_ 64

typedef unsigned short u16;
typedef unsigned int u32;
typedef __attribute__((ext_vector_type(8))) short short8;
typedef __attribute__((ext_vector_type(4))) float f32x4;
typedef __attribute__((ext_vector_type(2))) u32 uint2v;
typedef __attribute__((ext_vector_type(4))) u32 uint4v;

typedef __attribute__((address_space(1))) const void* as1cv;
typedef __attribute__((address_space(3))) void* as3v;

__device__ __forceinline__ u16 f2bf(float x){
  union { float f; u32 u; } v; v.f = x;
  u32 r = v.u + 0x7fffu + ((v.u >> 16) & 1u);
  return (u16)(r >> 16);
}
__device__ __forceinline__ float bf2f(u16 h){
  union { u32 u; float f; } v; v.u = ((u32)h) << 16;
  return v.f;
}
// packed f32x2 -> bf16x2 (RTNE), single VALU inst
__device__ __forceinline__ u32 cvt_pk_bf16(float lo, float hi){
  u32 r;
  asm("v_cvt_pk_bf16_f32 %0, %1, %2" : "=v"(r) : "v"(lo), "v"(hi));
  return r;
}
__device__ __forceinline__ void gl_lds16(const u16* src, u16* dst){
  __builtin_amdgcn_global_load_lds((as1cv)src, (as3v)dst, 16, 0, 0);
}

// ---------------- f32 -> bf16 convert (x4 vectorized) ----------------
__global__ void k_conv(const float* __restrict__ in, u16* __restrict__ out){
  int i = blockIdx.x * 256 + threadIdx.x;
  f32x4 v = ((const f32x4*)in)[i];
  uint2v o;
  o.x = (u32)f2bf(v.x) | ((u32)f2bf(v.y) << 16);
  o.y = (u32)f2bf(v.z) | ((u32)f2bf(v.w) << 16);
  ((uint2v*)out)[i] = o;
}

// ------------- transpose + convert: out[c][r] = bf16(in[r][c]) -------------
__global__ void k_transpose(const float* __restrict__ in, u16* __restrict__ out,
                            int R, int Cc){
  __shared__ float tile[32][33];
  int c0 = blockIdx.x * 32, r0 = blockIdx.y * 32;
  int tx = threadIdx.x, ty = threadIdx.y;
#pragma unroll
  for (int ii = 0; ii < 4; ++ii)
    tile[ty + ii*8][tx] = in[(size_t)(r0 + ty + ii*8) * Cc + c0 + tx];
  __syncthreads();
#pragma unroll
  for (int ii = 0; ii < 4; ++ii)
    out[(size_t)(c0 + ty + ii*8) * R + r0 + tx] = f2bf(tile[tx][ty + ii*8]);
}

// ---------------- QKV GEMM + fused RoPE epilogue ----------------
// R10 structure + T2 XOR swizzle (both-sides): staging reads global column
// chunk (slot ^ (row&7)) into linear LDS; fragment read fetches chunk
// ((ks*4+g) ^ (c&7)) — row&7 == c&7 for every fragment row. Eliminates the
// ~8-way ds_read_b128 bank conflict (9.4M cy) that saturated the LDS pipe.
__global__ __launch_bounds__(256, 3)
void k_gemm0(const u16* __restrict__ A, const u16* __restrict__ Bt,
             const float* __restrict__ bias, u16* __restrict__ Qh,
             u16* __restrict__ Kh, u16* __restrict__ vt,
             int M, int N, int K)
{
  __shared__ u16 As[128*64];
  __shared__ u16 Bs[128*64];
  int nwg = gridDim.x;
  int cpx = nwg >> 3;
  int bid = blockIdx.x;
  int wg = (bid & 7) * cpx + (bid >> 3);   // bijective XCD swizzle (nwg%8==0)
  int ntn = N >> 7;
  int m0 = (wg / ntn) << 7, n0 = (wg % ntn) << 7;
  int tid = threadIdx.x;
  int lane = tid & 63, w = tid >> 6;
  int c = lane & 15, g = lane >> 4;
  int wr = w >> 1, wc = w & 1;
  int c7 = c & 7;

  f32x4 z4 = {0.f,0.f,0.f,0.f};
  f32x4 acc[4][4];
#pragma unroll
  for (int i=0;i<4;++i)
#pragma unroll
    for (int j=0;j<4;++j) acc[i][j] = z4;

  u16* dstA = As + ((tid & 0xC0) << 3);
  u16* dstB = Bs + ((tid & 0xC0) << 3);
  int rowS[4], soffS[4];
#pragma unroll
  for (int it=0; it<4; ++it){
    int ch = it*256 + tid;
    rowS[it] = ch >> 3;
    soffS[it] = (((ch & 7) ^ (rowS[it] & 7)) << 3);   // pre-swizzled src chunk
  }

  for (int k0 = 0; k0 < K; k0 += 64){
#pragma unroll
    for (int it = 0; it < 4; ++it)
      gl_lds16(A + (size_t)(m0+rowS[it])*K + k0 + soffS[it], dstA + it*2048);
#pragma unroll
    for (int it = 0; it < 4; ++it)
      gl_lds16(Bt + (size_t)(n0+rowS[it])*K + k0 + soffS[it], dstB + it*2048);
    __syncthreads();
#pragma unroll
    for (int ks = 0; ks < 2; ++ks){
      short8 af[4], bf[4];
      int sx = ((ks*4 + g) ^ c7) << 3;                // swizzled read chunk
#pragma unroll
      for (int i=0;i<4;++i)
        af[i] = *(const short8*)(As + (wr*64 + i*16 + c)*64 + sx);
#pragma unroll
      for (int j=0;j<4;++j)
        bf[j] = *(const short8*)(Bs + (wc*64 + j*16 + c)*64 + sx);
#pragma unroll
      for (int i=0;i<4;++i)
#pragma unroll
        for (int j=0;j<4;++j)
          acc[i][j] = __builtin_amdgcn_mfma_f32_16x16x32_bf16(af[i], bf[j], acc[i][j], 0, 0, 0);
    }
    __syncthreads();
  }

  if (n0 >= 2048){
    // V section -> vt[bh][d][t], 4 consecutive t packed per 8B store
#pragma unroll
    for (int i=0;i<4;++i){
      int rowb = m0 + wr*64 + i*16 + g*4;
      int bb = rowb >> 11, t0 = rowb & 2047;
#pragma unroll
      for (int j=0;j<4;++j){
        int col = n0 + wc*64 + j*16 + c;
        float bv = bias[col];
        int vc = col - 2048;
        int hh = vc >> 6, d = vc & 63;
        uint2v o;
        o.x = (u32)f2bf(acc[i][j].x + bv) | ((u32)f2bf(acc[i][j].y + bv) << 16);
        o.y = (u32)f2bf(acc[i][j].z + bv) | ((u32)f2bf(acc[i][j].w + bv) << 16);
        *(uint2v*)(vt + ((size_t)((bb*16 + hh)*64 + d))*2048 + t0) = o;
      }
    }
  } else {
    // Q/K section: fused RoPE + head-split write
    bool isQ = (n0 < 1024);
    u16* dsth = isQ ? Qh : Kh;
    int colb = isQ ? n0 : (n0 - 1024);
    float qsc = isQ ? 0.180336880f : 1.0f;  // 0.125 * log2(e) on Q only
    float sgn = (c & 1) ? 1.f : -1.f;
#pragma unroll
    for (int nf=0; nf<4; ++nf){
      int scol = colb + wc*64 + nf*16 + c;
      int hh = scol >> 6, d = scol & 63;
      int ip = (d >> 1);
      float invr = exp2f((float)(-ip) * 0.4152410118609203f) * 0.15915494309f;
      float bv = bias[n0 + wc*64 + nf*16 + c];
      u16* base = dsth + (size_t)hh*2048*64 + d;
#pragma unroll
      for (int mf=0; mf<4; ++mf){
#pragma unroll
        for (int r=0; r<4; ++r){
          int row = m0 + wr*64 + mf*16 + g*4 + r;
          int t = row & 2047, b = row >> 11;
          float v = acc[mf][nf][r] + bv;
          float p = __shfl_xor(v, 1);
          float th = (float)t * invr;
          float fr = th - floorf(th);
          float sn = __builtin_amdgcn_sinf(fr);
          float cs = __builtin_amdgcn_cosf(fr);
          float y = (v*cs + p*sn*sgn) * qsc;
          base[((size_t)b*16*2048 + t)*64] = f2bf(y);
        }
      }
    }
  }
}

// ---------------- proj GEMM: out = Y * Wp^T + bias ----------------
// 64x128 tile, grid 512, double-buffered, + T2 XOR swizzle (both-sides).
__global__ __launch_bounds__(256, 3)
void k_gemmp(const u16* __restrict__ A, const u16* __restrict__ Bt,
             const float* __restrict__ bias, float* __restrict__ outf)
{
  __shared__ u16 LDSG[24576];     // A0@0 A1@4096 | B0@8192 B1@16384 (u16 idx)
  const int K = 1024, N = 1024;
  int nwg = gridDim.x;            // 512
  int cpx = nwg >> 3;
  int bid = blockIdx.x;
  int wg = (bid & 7) * cpx + (bid >> 3);
  int m0 = (wg >> 3) << 6, n0 = (wg & 7) << 7;
  int tid = threadIdx.x;
  int lane = tid & 63, w = tid >> 6;
  int c = lane & 15, g = lane >> 4;
  int wr = w >> 1, wc = w & 1;
  int c7 = c & 7;

  f32x4 z4 = {0.f,0.f,0.f,0.f};
  f32x4 acc[2][4];
#pragma unroll
  for (int i=0;i<2;++i)
#pragma unroll
    for (int j=0;j<4;++j) acc[i][j] = z4;

  int rowA[2], slotA[2], dstA[2];
#pragma unroll
  for (int it=0; it<2; ++it){
    int ch = it*256 + tid;
    rowA[it] = ch >> 3;
    slotA[it] = (((ch & 7) ^ (rowA[it] & 7)) << 3);
    dstA[it] = it*2048 + ((tid & 0xC0) << 3);
  }
  int rowB[4], slotB[4], dstB[4];
#pragma unroll
  for (int it=0; it<4; ++it){
    int ch = it*256 + tid;
    rowB[it] = ch >> 3;
    slotB[it] = (((ch & 7) ^ (rowB[it] & 7)) << 3);
    dstB[it] = 8192 + it*2048 + ((tid & 0xC0) << 3);
  }
  const u16* Abase = A + (size_t)m0*K;
  const u16* Bbase = Bt + (size_t)n0*K;

  // prologue: stage K-tile 0 into buf 0
#pragma unroll
  for (int it=0; it<2; ++it)
    gl_lds16(Abase + (size_t)rowA[it]*K + slotA[it], LDSG + dstA[it]);
#pragma unroll
  for (int it=0; it<4; ++it)
    gl_lds16(Bbase + (size_t)rowB[it]*K + slotB[it], LDSG + dstB[it]);
  __syncthreads();

  const int nk = K >> 6;
  for (int kt = 0; kt < nk; ++kt){
    int cur = kt & 1;
    if (kt + 1 < nk){
      int k1 = (kt + 1) << 6;
      int nb = cur ^ 1;
#pragma unroll
      for (int it=0; it<2; ++it)
        gl_lds16(Abase + (size_t)rowA[it]*K + k1 + slotA[it], LDSG + nb*4096 + dstA[it]);
#pragma unroll
      for (int it=0; it<4; ++it)
        gl_lds16(Bbase + (size_t)rowB[it]*K + k1 + slotB[it], LDSG + nb*8192 + dstB[it]);
    }
    const u16* As = LDSG + cur*4096;
    const u16* Bs = LDSG + 8192 + cur*8192;
#pragma unroll
    for (int ks = 0; ks < 2; ++ks){
      short8 af[2], bf[4];
      int sx = ((ks*4 + g) ^ c7) << 3;
#pragma unroll
      for (int i=0;i<2;++i)
        af[i] = *(const short8*)(As + (wr*32 + i*16 + c)*64 + sx);
#pragma unroll
      for (int j=0;j<4;++j)
        bf[j] = *(const short8*)(Bs + (wc*64 + j*16 + c)*64 + sx);
#pragma unroll
      for (int i=0;i<2;++i)
#pragma unroll
        for (int j=0;j<4;++j)
          acc[i][j] = __builtin_amdgcn_mfma_f32_16x16x32_bf16(af[i], bf[j], acc[i][j], 0, 0, 0);
    }
    __syncthreads();
  }

#pragma unroll
  for (int i=0;i<2;++i){
#pragma unroll
    for (int j=0;j<4;++j){
      int col = n0 + wc*64 + j*16 + c;
      float bv = bias[col];
#pragma unroll
      for (int r=0;r<4;++r){
        int row = m0 + wr*32 + i*16 + g*4 + r;
        outf[(size_t)row*N + col] = acc[i][j][r] + bv;
      }
    }
  }
}

// ---------------- causal flash attention, ADAPTIVE KV-split (unchanged) ----------------
__global__ __launch_bounds__(256, 3)
void k_attn(const u16* __restrict__ Qh, const u16* __restrict__ Kh,
            const u16* __restrict__ Vt, u16* __restrict__ Pb,
            float* __restrict__ lp)
{
  __shared__ u16 KV[4*4096];     // [K0 | K1 | V0 | V1], XOR-swizzled 16B chunks
  __shared__ u16 Ps[4*32*64];    // per-wave P[q][kv], XOR-swizzled

  int bid = blockIdx.x;
  int qt, ck, bh, l2nsp;
  if (bid < 1536){
    qt = 15 - (bid >> 7); ck = (bid >> 5) & 3; bh = bid & 31; l2nsp = 2;
  } else if (bid < 1728){
    int x = bid - 1536;
    qt = 3 - (x >> 6); ck = (x >> 5) & 1; bh = x & 31; l2nsp = 1;
  } else {
    qt = 0; ck = 0; bh = (bid - 1728) & 31; l2nsp = 0;
  }
  int q0 = qt << 7;
  int tid = threadIdx.x, lane = tid & 63, w = tid >> 6;
  int c = lane & 15, g = lane >> 4;
  int q0w = q0 + w*32;
  int nt = (qt + 1) << 1;
  int t0 = (nt * ck) >> l2nsp;
  int t1 = (nt * (ck + 1)) >> l2nsp;

  const u16* Kbase = Kh + (size_t)bh * T_ * 64;
  const u16* Vbase = Vt + (size_t)bh * 64 * T_;
  const u16* Qbase = Qh + (size_t)bh * T_ * 64;

  short8 qf[2][2];
#pragma unroll
  for (int qs=0;qs<2;++qs)
#pragma unroll
    for (int ks=0;ks<2;++ks)
      qf[qs][ks] = *(const short8*)(Qbase + (size_t)(q0w + qs*16 + c)*64 + ks*32 + g*8);

  f32x4 z4 = {0.f,0.f,0.f,0.f};
  f32x4 acc[2][4];
#pragma unroll
  for (int qs=0;qs<2;++qs)
#pragma unroll
    for (int ds=0;ds<4;++ds) acc[qs][ds] = z4;
  float psum[2] = {0.f, 0.f};

  char* PsB = (char*)Ps + w*4096;

  int row2[2], soff2[2];
  u16* dst0[2];
#pragma unroll
  for (int it=0; it<2; ++it){
    int ch = it*256 + tid;
    row2[it] = ch >> 3;
    int slot = ch & 7;
    soff2[it] = (slot ^ (row2[it] & 7)) << 3;
    dst0[it] = KV + ((it*256 + (tid & 0xC0)) << 3);
  }

  {
    int kv0 = t0 << 6;
#pragma unroll
    for (int it=0; it<2; ++it){
      gl_lds16(Kbase + (size_t)(kv0 + row2[it])*64 + soff2[it], dst0[it]);
      gl_lds16(Vbase + (size_t)row2[it]*T_ + kv0 + soff2[it], dst0[it] + 2*4096);
    }
  }
  __syncthreads();

  for (int t = t0; t < t1; ++t){
    int cur = (t - t0) & 1;
    int kv0 = t << 6;
    if (t + 1 < t1){
      int kvn = kv0 + 64;
      int nxt = cur ^ 1;
#pragma unroll
      for (int it=0; it<2; ++it){
        gl_lds16(Kbase + (size_t)(kvn + row2[it])*64 + soff2[it], dst0[it] + nxt*4096);
        gl_lds16(Vbase + (size_t)row2[it]*T_ + kvn + soff2[it], dst0[it] + (2+nxt)*4096);
      }
    }

    if (kv0 <= q0w + 31){   // wave-uniform: this wave has unmasked work
      const char* KsC = (const char*)(KV + cur*4096);
      const char* VsC = (const char*)(KV + (2+cur)*4096);

      f32x4 st[4][2];
#pragma unroll
      for (int kv=0;kv<4;++kv)
#pragma unroll
        for (int qs=0;qs<2;++qs) st[kv][qs] = z4;

#pragma unroll
      for (int ks=0;ks<2;++ks){
        short8 kf[4];
#pragma unroll
        for (int kv=0;kv<4;++kv){
          int row = kv*16 + c;
          kf[kv] = *(const short8*)(KsC + row*128 + (((ks*4+g) ^ (row&7)) << 4));
        }
#pragma unroll
        for (int kv=0;kv<4;++kv)
#pragma unroll
          for (int qs=0;qs<2;++qs)
            st[kv][qs] = __builtin_amdgcn_mfma_f32_16x16x32_bf16(kf[kv], qf[qs][ks], st[kv][qs], 0, 0, 0);
      }

      if (kv0 + 63 > q0w){  // diagonal tile: causal mask
#pragma unroll
        for (int kv=0;kv<4;++kv)
#pragma unroll
          for (int qs=0;qs<2;++qs)
#pragma unroll
            for (int r=0;r<4;++r){
              int kvi = kv0 + kv*16 + g*4 + r;
              int qi = q0w + qs*16 + c;
              if (kvi > qi) st[kv][qs][r] = -INFINITY;
            }
      }

#pragma unroll
      for (int qs=0;qs<2;++qs){
        float s01 = 0.f, s23 = 0.f;
#pragma unroll
        for (int kv=0;kv<4;++kv){
          float e0 = __builtin_amdgcn_exp2f(st[kv][qs][0]);
          float e1 = __builtin_amdgcn_exp2f(st[kv][qs][1]);
          float e2 = __builtin_amdgcn_exp2f(st[kv][qs][2]);
          float e3 = __builtin_amdgcn_exp2f(st[kv][qs][3]);
          st[kv][qs][0] = e0; st[kv][qs][1] = e1;
          st[kv][qs][2] = e2; st[kv][qs][3] = e3;
          s01 += e0 + e1; s23 += e2 + e3;
        }
        psum[qs] += s01 + s23;
        int q = qs*16 + c;
#pragma unroll
        for (int kv=0;kv<4;++kv){
          uint2v o;
          o.x = cvt_pk_bf16(st[kv][qs][0], st[kv][qs][1]);
          o.y = cvt_pk_bf16(st[kv][qs][2], st[kv][qs][3]);
          *(uint2v*)(PsB + q*128 + ((kv*32 + g*8) ^ ((q&7) << 4))) = o;
        }
      }

#pragma unroll
      for (int ks=0;ks<2;++ks){
        short8 vb[4];
#pragma unroll
        for (int ds=0;ds<4;++ds){
          int row = ds*16 + c;
          vb[ds] = *(const short8*)(VsC + row*128 + (((ks*4+g) ^ (row&7)) << 4));
        }
#pragma unroll
        for (int qs=0;qs<2;++qs){
          int q = qs*16 + c;
          short8 pa = *(const short8*)(PsB + q*128 + (((ks*4+g) << 4) ^ ((q&7) << 4)));
#pragma unroll
          for (int ds=0;ds<4;++ds)
            acc[qs][ds] = __builtin_amdgcn_mfma_f32_16x16x32_bf16(pa, vb[ds], acc[qs][ds], 0, 0, 0);
        }
      }
    }

    __syncthreads();
  }

#pragma unroll
  for (int qs=0;qs<2;++qs){
    psum[qs] += __shfl_xor(psum[qs], 16);
    psum[qs] += __shfl_xor(psum[qs], 32);
  }
  if (g == 0){
    lp[ck*65536 + bh*2048 + q0w + c]      = psum[0];
    lp[ck*65536 + bh*2048 + q0w + 16 + c] = psum[1];
  }
#pragma unroll
  for (int qs=0;qs<2;++qs){
#pragma unroll
    for (int r=0;r<4;++r){
      int trow = q0w + qs*16 + g*4 + r;
      size_t off = (((size_t)(ck*32 + bh)*2048) + trow)*64;
#pragma unroll
      for (int ds=0;ds<4;++ds)
        Pb[off + ds*16 + c] = f2bf(acc[qs][ds][r]);
    }
  }
}

// ---------------- merge partials (variable split count per qt) ----------------
__global__ void k_merge(const u16* __restrict__ Pb, const float* __restrict__ lp,
                        u16* __restrict__ Y)
{
  int idx = blockIdx.x * 256 + threadIdx.x;
  int d8 = idx & 7;
  int t  = (idx >> 3) & 2047;
  int bh = idx >> 14;
  int qt = t >> 7;
  int lt = bh*2048 + t;
  float s[8];
  float l = lp[lt];
  {
    short8 p = *(const short8*)(Pb + (((size_t)bh*2048 + t) << 6) + d8*8);
#pragma unroll
    for (int j=0;j<8;++j) s[j] = bf2f((u16)p[j]);
  }
  if (qt >= 1){
    l += lp[lt + 65536];
    short8 p = *(const short8*)(Pb + (((size_t)(32 + bh)*2048 + t) << 6) + d8*8);
#pragma unroll
    for (int j=0;j<8;++j) s[j] += bf2f((u16)p[j]);
  }
  if (qt >= 4){
    l += lp[lt + 131072] + lp[lt + 196608];
    short8 p2 = *(const short8*)(Pb + (((size_t)(64 + bh)*2048 + t) << 6) + d8*8);
    short8 p3 = *(const short8*)(Pb + (((size_t)(96 + bh)*2048 + t) << 6) + d8*8);
#pragma unroll
    for (int j=0;j<8;++j) s[j] += bf2f((u16)p2[j]) + bf2f((u16)p3[j]);
  }
  float inv = 1.0f / l;
  uint4v o;
  o.x = cvt_pk_bf16(s[0]*inv, s[1]*inv);
  o.y = cvt_pk_bf16(s[2]*inv, s[3]*inv);
  o.z = cvt_pk_bf16(s[4]*inv, s[5]*inv);
  o.w = cvt_pk_bf16(s[6]*inv, s[7]*inv);
  int bb = bh >> 4, hh = bh & 15;
  *(uint4v*)(Y + ((size_t)(bb*2048 + t))*1024 + hh*64 + d8*8) = o;
}

extern "C" void kernel_launch(void* const* d_in, const int* in_sizes, int n_in,
                              void* d_out, int out_size, void* d_ws, size_t ws_size,
                              hipStream_t stream)
{
  const float* x  = (const float*)d_in[0];
  const float* Wa = (const float*)d_in[1];
  const float* ba = (const float*)d_in[2];
  const float* Wp = (const float*)d_in[3];
  const float* bp = (const float*)d_in[4];
  float* out = (float*)d_out;
  char* ws = (char*)d_ws;

  // workspace layout (59 MB peak, lifetime-overlaid):
  //  phase1: xb [0,8) + WaT [8,14)    (dead after gemm0)
  //  attn:   Pb [0,32) bf16 partials [4][32][2048][64] (slots per qt's nsp)
  //  [32,40) Qh   | after attn: Y (merge output)
  //  [40,48) Kh
  //  [48,56) Vt
  //  [56,58) WpT
  //  [58,59) lp f32 [4][32][2048]
  u16* xb  = (u16*)(ws);
  u16* WaT = (u16*)(ws + (8u  << 20));
  u16* Pb  = (u16*)(ws);
  u16* Qh  = (u16*)(ws + (32u << 20));
  u16* Y   = Qh;
  u16* Kh  = (u16*)(ws + (40u << 20));
  u16* Vt  = (u16*)(ws + (48u << 20));
  u16* WpT = (u16*)(ws + (56u << 20));
  float* lp = (float*)(ws + (58u << 20));

  k_conv<<<4096, 256, 0, stream>>>(x, xb);
  k_transpose<<<dim3(96,32), dim3(32,8), 0, stream>>>(Wa, WaT, 1024, 3072);
  k_transpose<<<dim3(32,32), dim3(32,8), 0, stream>>>(Wp, WpT, 1024, 1024);
  k_gemm0<<<768, 256, 0, stream>>>(xb, WaT, ba, Qh, Kh, Vt, 4096, 3072, 1024);
  k_attn<<<1760, 256, 0, stream>>>(Qh, Kh, Vt, Pb, lp);
  k_merge<<<2048, 256, 0, stream>>>(Pb, lp, Y);
  k_gemmp<<<512, 256, 0, stream>>>(Y, WpT, bp, out);
}

// Round 14
// 95.177 us; speedup vs baseline: 1.2307x; 1.0406x over previous
//
#include <hip/hip_runtime.h>

#define B_ 2
#define T_ 2048
#define C_ 1024
#define H_ 16
#define HD_ 64

typedef unsigned short u16;
typedef unsigned int u32;
typedef __attribute__((ext_vector_type(8))) short short8;
typedef __attribute__((ext_vector_type(4))) float f32x4;
typedef __attribute__((ext_vector_type(2))) u32 uint2v;
typedef __attribute__((ext_vector_type(4))) u32 uint4v;

typedef __attribute__((address_space(1))) const void* as1cv;
typedef __attribute__((address_space(3))) void* as3v;

__device__ __forceinline__ u16 f2bf(float x){
  union { float f; u32 u; } v; v.f = x;
  u32 r = v.u + 0x7fffu + ((v.u >> 16) & 1u);
  return (u16)(r >> 16);
}
__device__ __forceinline__ float bf2f(u16 h){
  union { u32 u; float f; } v; v.u = ((u32)h) << 16;
  return v.f;
}
// packed f32x2 -> bf16x2 (RTNE), single VALU inst
__device__ __forceinline__ u32 cvt_pk_bf16(float lo, float hi){
  u32 r;
  asm("v_cvt_pk_bf16_f32 %0, %1, %2" : "=v"(r) : "v"(lo), "v"(hi));
  return r;
}
__device__ __forceinline__ void gl_lds16(const u16* src, u16* dst){
  __builtin_amdgcn_global_load_lds((as1cv)src, (as3v)dst, 16, 0, 0);
}

// -------- fused preprocessing: x->bf16 conv + Wa^T + Wp^T (one dispatch) --------
// blocks [0,4096): conv (256 f32x4 groups each)
// blocks [4096,7168): Wa transpose 32x32 tiles (96 x 32 tile grid)
// blocks [7168,8192): Wp transpose (32 x 32 tile grid)
__global__ void k_prep(const float* __restrict__ x, u16* __restrict__ xb,
                       const float* __restrict__ Wa, u16* __restrict__ WaT,
                       const float* __restrict__ Wp, u16* __restrict__ WpT)
{
  __shared__ float tile[32][33];
  int b = blockIdx.x;
  int tid = threadIdx.x;
  if (b < 4096){
    int i = b*256 + tid;
    f32x4 v = ((const f32x4*)x)[i];
    uint2v o;
    o.x = (u32)f2bf(v.x) | ((u32)f2bf(v.y) << 16);
    o.y = (u32)f2bf(v.z) | ((u32)f2bf(v.w) << 16);
    ((uint2v*)xb)[i] = o;
    return;
  }
  const float* in; u16* out; int R, Cc, c0, r0;
  if (b < 7168){
    int bb = b - 4096;              // 96 x 32 tiles
    in = Wa; out = WaT; R = 1024; Cc = 3072;
    c0 = (bb % 96) * 32; r0 = (bb / 96) * 32;
  } else {
    int bb = b - 7168;              // 32 x 32 tiles
    in = Wp; out = WpT; R = 1024; Cc = 1024;
    c0 = (bb & 31) * 32; r0 = (bb >> 5) * 32;
  }
  int tx = tid & 31, ty = tid >> 5;
#pragma unroll
  for (int ii = 0; ii < 4; ++ii)
    tile[ty + ii*8][tx] = in[(size_t)(r0 + ty + ii*8) * Cc + c0 + tx];
  __syncthreads();
#pragma unroll
  for (int ii = 0; ii < 4; ++ii)
    out[(size_t)(c0 + ty + ii*8) * R + r0 + tx] = f2bf(tile[tx][ty + ii*8]);
}

// ---------------- QKV GEMM + fused RoPE epilogue (unchanged from R12) ----------------
__global__ __launch_bounds__(256, 3)
void k_gemm0(const u16* __restrict__ A, const u16* __restrict__ Bt,
             const float* __restrict__ bias, u16* __restrict__ Qh,
             u16* __restrict__ Kh, u16* __restrict__ vt,
             int M, int N, int K)
{
  __shared__ u16 As[128*64];
  __shared__ u16 Bs[128*64];
  int nwg = gridDim.x;
  int cpx = nwg >> 3;
  int bid = blockIdx.x;
  int wg = (bid & 7) * cpx + (bid >> 3);   // bijective XCD swizzle (nwg%8==0)
  int ntn = N >> 7;
  int m0 = (wg / ntn) << 7, n0 = (wg % ntn) << 7;
  int tid = threadIdx.x;
  int lane = tid & 63, w = tid >> 6;
  int c = lane & 15, g = lane >> 4;
  int wr = w >> 1, wc = w & 1;
  int c7 = c & 7;

  f32x4 z4 = {0.f,0.f,0.f,0.f};
  f32x4 acc[4][4];
#pragma unroll
  for (int i=0;i<4;++i)
#pragma unroll
    for (int j=0;j<4;++j) acc[i][j] = z4;

  u16* dstA = As + ((tid & 0xC0) << 3);
  u16* dstB = Bs + ((tid & 0xC0) << 3);
  int rowS[4], soffS[4];
#pragma unroll
  for (int it=0; it<4; ++it){
    int ch = it*256 + tid;
    rowS[it] = ch >> 3;
    soffS[it] = (((ch & 7) ^ (rowS[it] & 7)) << 3);   // pre-swizzled src chunk
  }

  for (int k0 = 0; k0 < K; k0 += 64){
#pragma unroll
    for (int it = 0; it < 4; ++it)
      gl_lds16(A + (size_t)(m0+rowS[it])*K + k0 + soffS[it], dstA + it*2048);
#pragma unroll
    for (int it = 0; it < 4; ++it)
      gl_lds16(Bt + (size_t)(n0+rowS[it])*K + k0 + soffS[it], dstB + it*2048);
    __syncthreads();
#pragma unroll
    for (int ks = 0; ks < 2; ++ks){
      short8 af[4], bf[4];
      int sx = ((ks*4 + g) ^ c7) << 3;                // swizzled read chunk
#pragma unroll
      for (int i=0;i<4;++i)
        af[i] = *(const short8*)(As + (wr*64 + i*16 + c)*64 + sx);
#pragma unroll
      for (int j=0;j<4;++j)
        bf[j] = *(const short8*)(Bs + (wc*64 + j*16 + c)*64 + sx);
#pragma unroll
      for (int i=0;i<4;++i)
#pragma unroll
        for (int j=0;j<4;++j)
          acc[i][j] = __builtin_amdgcn_mfma_f32_16x16x32_bf16(af[i], bf[j], acc[i][j], 0, 0, 0);
    }
    __syncthreads();
  }

  if (n0 >= 2048){
    // V section -> vt[bh][d][t], 4 consecutive t packed per 8B store
#pragma unroll
    for (int i=0;i<4;++i){
      int rowb = m0 + wr*64 + i*16 + g*4;
      int bb = rowb >> 11, t0 = rowb & 2047;
#pragma unroll
      for (int j=0;j<4;++j){
        int col = n0 + wc*64 + j*16 + c;
        float bv = bias[col];
        int vc = col - 2048;
        int hh = vc >> 6, d = vc & 63;
        uint2v o;
        o.x = (u32)f2bf(acc[i][j].x + bv) | ((u32)f2bf(acc[i][j].y + bv) << 16);
        o.y = (u32)f2bf(acc[i][j].z + bv) | ((u32)f2bf(acc[i][j].w + bv) << 16);
        *(uint2v*)(vt + ((size_t)((bb*16 + hh)*64 + d))*2048 + t0) = o;
      }
    }
  } else {
    // Q/K section: fused RoPE + head-split write
    bool isQ = (n0 < 1024);
    u16* dsth = isQ ? Qh : Kh;
    int colb = isQ ? n0 : (n0 - 1024);
    float qsc = isQ ? 0.180336880f : 1.0f;  // 0.125 * log2(e) on Q only
    float sgn = (c & 1) ? 1.f : -1.f;
#pragma unroll
    for (int nf=0; nf<4; ++nf){
      int scol = colb + wc*64 + nf*16 + c;
      int hh = scol >> 6, d = scol & 63;
      int ip = (d >> 1);
      float invr = exp2f((float)(-ip) * 0.4152410118609203f) * 0.15915494309f;
      float bv = bias[n0 + wc*64 + nf*16 + c];
      u16* base = dsth + (size_t)hh*2048*64 + d;
#pragma unroll
      for (int mf=0; mf<4; ++mf){
#pragma unroll
        for (int r=0; r<4; ++r){
          int row = m0 + wr*64 + mf*16 + g*4 + r;
          int t = row & 2047, b = row >> 11;
          float v = acc[mf][nf][r] + bv;
          float p = __shfl_xor(v, 1);
          float th = (float)t * invr;
          float fr = th - floorf(th);
          float sn = __builtin_amdgcn_sinf(fr);
          float cs = __builtin_amdgcn_cosf(fr);
          float y = (v*cs + p*sn*sgn) * qsc;
          base[((size_t)b*16*2048 + t)*64] = f2bf(y);
        }
      }
    }
  }
}

// ---------------- proj GEMM: out = Y * Wp^T + bias (unchanged from R12) ----------------
__global__ __launch_bounds__(256, 3)
void k_gemmp(const u16* __restrict__ A, const u16* __restrict__ Bt,
             const float* __restrict__ bias, float* __restrict__ outf)
{
  __shared__ u16 LDSG[24576];     // A0@0 A1@4096 | B0@8192 B1@16384 (u16 idx)
  const int K = 1024, N = 1024;
  int nwg = gridDim.x;            // 512
  int cpx = nwg >> 3;
  int bid = blockIdx.x;
  int wg = (bid & 7) * cpx + (bid >> 3);
  int m0 = (wg >> 3) << 6, n0 = (wg & 7) << 7;
  int tid = threadIdx.x;
  int lane = tid & 63, w = tid >> 6;
  int c = lane & 15, g = lane >> 4;
  int wr = w >> 1, wc = w & 1;
  int c7 = c & 7;

  f32x4 z4 = {0.f,0.f,0.f,0.f};
  f32x4 acc[2][4];
#pragma unroll
  for (int i=0;i<2;++i)
#pragma unroll
    for (int j=0;j<4;++j) acc[i][j] = z4;

  int rowA[2], slotA[2], dstA[2];
#pragma unroll
  for (int it=0; it<2; ++it){
    int ch = it*256 + tid;
    rowA[it] = ch >> 3;
    slotA[it] = (((ch & 7) ^ (rowA[it] & 7)) << 3);
    dstA[it] = it*2048 + ((tid & 0xC0) << 3);
  }
  int rowB[4], slotB[4], dstB[4];
#pragma unroll
  for (int it=0; it<4; ++it){
    int ch = it*256 + tid;
    rowB[it] = ch >> 3;
    slotB[it] = (((ch & 7) ^ (rowB[it] & 7)) << 3);
    dstB[it] = 8192 + it*2048 + ((tid & 0xC0) << 3);
  }
  const u16* Abase = A + (size_t)m0*K;
  const u16* Bbase = Bt + (size_t)n0*K;

  // prologue: stage K-tile 0 into buf 0
#pragma unroll
  for (int it=0; it<2; ++it)
    gl_lds16(Abase + (size_t)rowA[it]*K + slotA[it], LDSG + dstA[it]);
#pragma unroll
  for (int it=0; it<4; ++it)
    gl_lds16(Bbase + (size_t)rowB[it]*K + slotB[it], LDSG + dstB[it]);
  __syncthreads();

  const int nk = K >> 6;
  for (int kt = 0; kt < nk; ++kt){
    int cur = kt & 1;
    if (kt + 1 < nk){
      int k1 = (kt + 1) << 6;
      int nb = cur ^ 1;
#pragma unroll
      for (int it=0; it<2; ++it)
        gl_lds16(Abase + (size_t)rowA[it]*K + k1 + slotA[it], LDSG + nb*4096 + dstA[it]);
#pragma unroll
      for (int it=0; it<4; ++it)
        gl_lds16(Bbase + (size_t)rowB[it]*K + k1 + slotB[it], LDSG + nb*8192 + dstB[it]);
    }
    const u16* As = LDSG + cur*4096;
    const u16* Bs = LDSG + 8192 + cur*8192;
#pragma unroll
    for (int ks = 0; ks < 2; ++ks){
      short8 af[2], bf[4];
      int sx = ((ks*4 + g) ^ c7) << 3;
#pragma unroll
      for (int i=0;i<2;++i)
        af[i] = *(const short8*)(As + (wr*32 + i*16 + c)*64 + sx);
#pragma unroll
      for (int j=0;j<4;++j)
        bf[j] = *(const short8*)(Bs + (wc*64 + j*16 + c)*64 + sx);
#pragma unroll
      for (int i=0;i<2;++i)
#pragma unroll
        for (int j=0;j<4;++j)
          acc[i][j] = __builtin_amdgcn_mfma_f32_16x16x32_bf16(af[i], bf[j], acc[i][j], 0, 0, 0);
    }
    __syncthreads();
  }

#pragma unroll
  for (int i=0;i<2;++i){
#pragma unroll
    for (int j=0;j<4;++j){
      int col = n0 + wc*64 + j*16 + c;
      float bv = bias[col];
#pragma unroll
      for (int r=0;r<4;++r){
        int row = m0 + wr*32 + i*16 + g*4 + r;
        outf[(size_t)row*N + col] = acc[i][j][r] + bv;
      }
    }
  }
}

// ---------------- causal flash attention, ADAPTIVE KV-split (R12 proven) ----------------
__global__ __launch_bounds__(256, 3)
void k_attn(const u16* __restrict__ Qh, const u16* __restrict__ Kh,
            const u16* __restrict__ Vt, u16* __restrict__ Pb,
            float* __restrict__ lp)
{
  __shared__ u16 KV[4*4096];     // [K0 | K1 | V0 | V1], XOR-swizzled 16B chunks
  __shared__ u16 Ps[4*32*64];    // per-wave P[q][kv], XOR-swizzled

  int bid = blockIdx.x;
  int qt, ck, bh, l2nsp;
  if (bid < 1536){
    qt = 15 - (bid >> 7); ck = (bid >> 5) & 3; bh = bid & 31; l2nsp = 2;
  } else if (bid < 1728){
    int x = bid - 1536;
    qt = 3 - (x >> 6); ck = (x >> 5) & 1; bh = x & 31; l2nsp = 1;
  } else {
    qt = 0; ck = 0; bh = (bid - 1728) & 31; l2nsp = 0;
  }
  int q0 = qt << 7;
  int tid = threadIdx.x, lane = tid & 63, w = tid >> 6;
  int c = lane & 15, g = lane >> 4;
  int q0w = q0 + w*32;
  int nt = (qt + 1) << 1;
  int t0 = (nt * ck) >> l2nsp;
  int t1 = (nt * (ck + 1)) >> l2nsp;

  const u16* Kbase = Kh + (size_t)bh * T_ * 64;
  const u16* Vbase = Vt + (size_t)bh * 64 * T_;
  const u16* Qbase = Qh + (size_t)bh * T_ * 64;

  short8 qf[2][2];
#pragma unroll
  for (int qs=0;qs<2;++qs)
#pragma unroll
    for (int ks=0;ks<2;++ks)
      qf[qs][ks] = *(const short8*)(Qbase + (size_t)(q0w + qs*16 + c)*64 + ks*32 + g*8);

  f32x4 z4 = {0.f,0.f,0.f,0.f};
  f32x4 acc[2][4];
#pragma unroll
  for (int qs=0;qs<2;++qs)
#pragma unroll
    for (int ds=0;ds<4;++ds) acc[qs][ds] = z4;
  float psum[2] = {0.f, 0.f};

  char* PsB = (char*)Ps + w*4096;

  int row2[2], soff2[2];
  u16* dst0[2];
#pragma unroll
  for (int it=0; it<2; ++it){
    int ch = it*256 + tid;
    row2[it] = ch >> 3;
    int slot = ch & 7;
    soff2[it] = (slot ^ (row2[it] & 7)) << 3;
    dst0[it] = KV + ((it*256 + (tid & 0xC0)) << 3);
  }

  {
    int kv0 = t0 << 6;
#pragma unroll
    for (int it=0; it<2; ++it){
      gl_lds16(Kbase + (size_t)(kv0 + row2[it])*64 + soff2[it], dst0[it]);
      gl_lds16(Vbase + (size_t)row2[it]*T_ + kv0 + soff2[it], dst0[it] + 2*4096);
    }
  }
  __syncthreads();

  for (int t = t0; t < t1; ++t){
    int cur = (t - t0) & 1;
    int kv0 = t << 6;
    if (t + 1 < t1){
      int kvn = kv0 + 64;
      int nxt = cur ^ 1;
#pragma unroll
      for (int it=0; it<2; ++it){
        gl_lds16(Kbase + (size_t)(kvn + row2[it])*64 + soff2[it], dst0[it] + nxt*4096);
        gl_lds16(Vbase + (size_t)row2[it]*T_ + kvn + soff2[it], dst0[it] + (2+nxt)*4096);
      }
    }

    if (kv0 <= q0w + 31){   // wave-uniform: this wave has unmasked work
      const char* KsC = (const char*)(KV + cur*4096);
      const char* VsC = (const char*)(KV + (2+cur)*4096);

      f32x4 st[4][2];
#pragma unroll
      for (int kv=0;kv<4;++kv)
#pragma unroll
        for (int qs=0;qs<2;++qs) st[kv][qs] = z4;

#pragma unroll
      for (int ks=0;ks<2;++ks){
        short8 kf[4];
#pragma unroll
        for (int kv=0;kv<4;++kv){
          int row = kv*16 + c;
          kf[kv] = *(const short8*)(KsC + row*128 + (((ks*4+g) ^ (row&7)) << 4));
        }
#pragma unroll
        for (int kv=0;kv<4;++kv)
#pragma unroll
          for (int qs=0;qs<2;++qs)
            st[kv][qs] = __builtin_amdgcn_mfma_f32_16x16x32_bf16(kf[kv], qf[qs][ks], st[kv][qs], 0, 0, 0);
      }

      if (kv0 + 63 > q0w){  // diagonal tile: causal mask
#pragma unroll
        for (int kv=0;kv<4;++kv)
#pragma unroll
          for (int qs=0;qs<2;++qs)
#pragma unroll
            for (int r=0;r<4;++r){
              int kvi = kv0 + kv*16 + g*4 + r;
              int qi = q0w + qs*16 + c;
              if (kvi > qi) st[kv][qs][r] = -INFINITY;
            }
      }

#pragma unroll
      for (int qs=0;qs<2;++qs){
        float s01 = 0.f, s23 = 0.f;
#pragma unroll
        for (int kv=0;kv<4;++kv){
          float e0 = __builtin_amdgcn_exp2f(st[kv][qs][0]);
          float e1 = __builtin_amdgcn_exp2f(st[kv][qs][1]);
          float e2 = __builtin_amdgcn_exp2f(st[kv][qs][2]);
          float e3 = __builtin_amdgcn_exp2f(st[kv][qs][3]);
          st[kv][qs][0] = e0; st[kv][qs][1] = e1;
          st[kv][qs][2] = e2; st[kv][qs][3] = e3;
          s01 += e0 + e1; s23 += e2 + e3;
        }
        psum[qs] += s01 + s23;
        int q = qs*16 + c;
#pragma unroll
        for (int kv=0;kv<4;++kv){
          uint2v o;
          o.x = cvt_pk_bf16(st[kv][qs][0], st[kv][qs][1]);
          o.y = cvt_pk_bf16(st[kv][qs][2], st[kv][qs][3]);
          *(uint2v*)(PsB + q*128 + ((kv*32 + g*8) ^ ((q&7) << 4))) = o;
        }
      }

#pragma unroll
      for (int ks=0;ks<2;++ks){
        short8 vb[4];
#pragma unroll
        for (int ds=0;ds<4;++ds){
          int row = ds*16 + c;
          vb[ds] = *(const short8*)(VsC + row*128 + (((ks*4+g) ^ (row&7)) << 4));
        }
#pragma unroll
        for (int qs=0;qs<2;++qs){
          int q = qs*16 + c;
          short8 pa = *(const short8*)(PsB + q*128 + (((ks*4+g) << 4) ^ ((q&7) << 4)));
#pragma unroll
          for (int ds=0;ds<4;++ds)
            acc[qs][ds] = __builtin_amdgcn_mfma_f32_16x16x32_bf16(pa, vb[ds], acc[qs][ds], 0, 0, 0);
        }
      }
    }

    __syncthreads();
  }

#pragma unroll
  for (int qs=0;qs<2;++qs){
    psum[qs] += __shfl_xor(psum[qs], 16);
    psum[qs] += __shfl_xor(psum[qs], 32);
  }
  if (g == 0){
    lp[ck*65536 + bh*2048 + q0w + c]      = psum[0];
    lp[ck*65536 + bh*2048 + q0w + 16 + c] = psum[1];
  }
#pragma unroll
  for (int qs=0;qs<2;++qs){
#pragma unroll
    for (int r=0;r<4;++r){
      int trow = q0w + qs*16 + g*4 + r;
      size_t off = (((size_t)(ck*32 + bh)*2048) + trow)*64;
#pragma unroll
      for (int ds=0;ds<4;++ds)
        Pb[off + ds*16 + c] = f2bf(acc[qs][ds][r]);
    }
  }
}

// ---------------- merge partials (variable split count per qt, R12 proven) ----------------
__global__ void k_merge(const u16* __restrict__ Pb, const float* __restrict__ lp,
                        u16* __restrict__ Y)
{
  int idx = blockIdx.x * 256 + threadIdx.x;
  int d8 = idx & 7;
  int t  = (idx >> 3) & 2047;
  int bh = idx >> 14;
  int qt = t >> 7;
  int lt = bh*2048 + t;
  float s[8];
  float l = lp[lt];
  {
    short8 p = *(const short8*)(Pb + (((size_t)bh*2048 + t) << 6) + d8*8);
#pragma unroll
    for (int j=0;j<8;++j) s[j] = bf2f((u16)p[j]);
  }
  if (qt >= 1){
    l += lp[lt + 65536];
    short8 p = *(const short8*)(Pb + (((size_t)(32 + bh)*2048 + t) << 6) + d8*8);
#pragma unroll
    for (int j=0;j<8;++j) s[j] += bf2f((u16)p[j]);
  }
  if (qt >= 4){
    l += lp[lt + 131072] + lp[lt + 196608];
    short8 p2 = *(const short8*)(Pb + (((size_t)(64 + bh)*2048 + t) << 6) + d8*8);
    short8 p3 = *(const short8*)(Pb + (((size_t)(96 + bh)*2048 + t) << 6) + d8*8);
#pragma unroll
    for (int j=0;j<8;++j) s[j] += bf2f((u16)p2[j]) + bf2f((u16)p3[j]);
  }
  float inv = 1.0f / l;
  uint4v o;
  o.x = cvt_pk_bf16(s[0]*inv, s[1]*inv);
  o.y = cvt_pk_bf16(s[2]*inv, s[3]*inv);
  o.z = cvt_pk_bf16(s[4]*inv, s[5]*inv);
  o.w = cvt_pk_bf16(s[6]*inv, s[7]*inv);
  int bb = bh >> 4, hh = bh & 15;
  *(uint4v*)(Y + ((size_t)(bb*2048 + t))*1024 + hh*64 + d8*8) = o;
}

extern "C" void kernel_launch(void* const* d_in, const int* in_sizes, int n_in,
                              void* d_out, int out_size, void* d_ws, size_t ws_size,
                              hipStream_t stream)
{
  const float* x  = (const float*)d_in[0];
  const float* Wa = (const float*)d_in[1];
  const float* ba = (const float*)d_in[2];
  const float* Wp = (const float*)d_in[3];
  const float* bp = (const float*)d_in[4];
  float* out = (float*)d_out;
  char* ws = (char*)d_ws;

  // workspace layout (59 MB peak, lifetime-overlaid):
  //  phase1: xb [0,8) + WaT [8,14)    (dead after gemm0)
  //  attn:   Pb [0,32) bf16 partials [4][32][2048][64] (slots per qt's nsp)
  //  [32,40) Qh   | after attn: Y (merge output)
  //  [40,48) Kh
  //  [48,56) Vt
  //  [56,58) WpT
  //  [58,59) lp f32 [4][32][2048]
  u16* xb  = (u16*)(ws);
  u16* WaT = (u16*)(ws + (8u  << 20));
  u16* Pb  = (u16*)(ws);
  u16* Qh  = (u16*)(ws + (32u << 20));
  u16* Y   = Qh;
  u16* Kh  = (u16*)(ws + (40u << 20));
  u16* Vt  = (u16*)(ws + (48u << 20));
  u16* WpT = (u16*)(ws + (56u << 20));
  float* lp = (float*)(ws + (58u << 20));

  k_prep<<<8192, 256, 0, stream>>>(x, xb, Wa, WaT, Wp, WpT);
  k_gemm0<<<768, 256, 0, stream>>>(xb, WaT, ba, Qh, Kh, Vt, 4096, 3072, 1024);
  k_attn<<<1760, 256, 0, stream>>>(Qh, Kh, Vt, Pb, lp);
  k_merge<<<2048, 256, 0, stream>>>(Pb, lp, Y);
  k_gemmp<<<512, 256, 0, stream>>>(Y, WpT, bp, out);
}